// Round 7
// baseline (674.985 us; speedup 1.0000x reference)
//
#include <hip/hip_runtime.h>
#include <cstdint>
#include <cstddef>

#define NT 256
#define DFEAT 128
#define SCAN_ELEMS 1024

typedef __attribute__((ext_vector_type(8))) short s8v;
typedef __attribute__((ext_vector_type(4))) float f32x4;

__device__ inline ushort f2bf(float f) {           // RNE fp32 -> bf16
  uint32_t u = __float_as_uint(f);
  u += 0x7fffu + ((u >> 16) & 1u);
  return (ushort)(u >> 16);
}

// ---------- zero int array ----------
__global__ void zero_k(int* __restrict__ p, int n) {
  int i = blockIdx.x * NT + threadIdx.x;
  if (i < n) p[i] = 0;
}

// ---------- histogram of dst, both graphs in one dispatch ----------
__global__ void hist2_k(const int* __restrict__ e_dst, int E,
                        const int* __restrict__ c_dst, int EC,
                        int* __restrict__ cnt_c, int* __restrict__ cnt_t) {
  int i = blockIdx.x * NT + threadIdx.x;
  if (i < E) atomicAdd(&cnt_c[e_dst[i]], 1);
  else if (i < E + EC) atomicAdd(&cnt_t[c_dst[i - E]], 1);
}

// ---------- dinv from histogram counts (before scan clobbers them) ----------
__global__ void dinv2_k(const int* __restrict__ cntc, const int* __restrict__ cntt,
                        float* __restrict__ dc, float* __restrict__ dt, int n) {
  int i = blockIdx.x * NT + threadIdx.x;
  if (i < n) {
    dc[i] = rsqrtf((float)(cntc[i] + 1));
    dt[i] = rsqrtf((float)(cntt[i] + 1));
  }
}

// ---------- scan pass A (split: blocks [0,nb) = conv, [nb,2nb) = ctrl) ----------
__global__ __launch_bounds__(NT) void scan_partial_k(
    const int* __restrict__ cnt_c, const int* __restrict__ cnt_t, int n,
    int* __restrict__ bsum, int nb_c) {
  int isT = blockIdx.x >= nb_c;
  const int* cnt = isT ? cnt_t : cnt_c;
  int b = isT ? blockIdx.x - nb_c : blockIdx.x;
  int base = b * SCAN_ELEMS + threadIdx.x * 4;

  int s = 0;
  if (base + 3 < n) {
    int4 v = *(const int4*)&cnt[base];
    s = v.x + v.y + v.z + v.w;
  } else {
    for (int j = 0; j < 4; j++) if (base + j < n) s += cnt[base + j];
  }
  for (int off = 32; off > 0; off >>= 1) s += __shfl_down(s, off, 64);
  __shared__ int ws[4];
  int lane = threadIdx.x & 63, w = threadIdx.x >> 6;
  if (lane == 0) ws[w] = s;
  __syncthreads();
  if (threadIdx.x == 0) bsum[blockIdx.x] = ws[0] + ws[1] + ws[2] + ws[3];
}

// ---------- scan pass B ----------
__global__ __launch_bounds__(NT) void scan_offsets_k(
    int* __restrict__ bsum, int nb_c, int nb_t,
    int* __restrict__ rp_c, int* __restrict__ rp_t, int n) {
  int seg_off = (blockIdx.x == 0) ? 0 : nb_c;
  int nb = (blockIdx.x == 0) ? nb_c : nb_t;
  int* rp = (blockIdx.x == 0) ? rp_c : rp_t;

  __shared__ int ls[NT];
  int t = threadIdx.x;
  int v = (t < nb) ? bsum[seg_off + t] : 0;
  ls[t] = v;
  __syncthreads();
  for (int off = 1; off < NT; off <<= 1) {
    int u = (t >= off) ? ls[t - off] : 0;
    __syncthreads();
    ls[t] += u;
    __syncthreads();
  }
  if (t < nb) bsum[seg_off + t] = ls[t] - v;
  if (t == nb - 1) rp[n] = ls[t];
}

// ---------- scan pass C: rowptr out; cursor array seeded with row offsets ----------
__global__ __launch_bounds__(NT) void scan_final_k(
    int* __restrict__ cnt_c, int* __restrict__ cnt_t, int n,
    const int* __restrict__ bsum, int nb_c,
    int* __restrict__ rp_c, int* __restrict__ rp_t) {
  int isT = blockIdx.x >= nb_c;
  int* cnt = isT ? cnt_t : cnt_c;
  int* rp = isT ? rp_t : rp_c;
  int b = isT ? blockIdx.x - nb_c : blockIdx.x;
  int offset = bsum[blockIdx.x];
  int base = b * SCAN_ELEMS + threadIdx.x * 4;

  int4 v = make_int4(0, 0, 0, 0);
  if (base + 3 < n) v = *(const int4*)&cnt[base];
  else { if (base + 0 < n) v.x = cnt[base + 0];
         if (base + 1 < n) v.y = cnt[base + 1];
         if (base + 2 < n) v.z = cnt[base + 2];
         if (base + 3 < n) v.w = cnt[base + 3]; }
  int tsum = v.x + v.y + v.z + v.w;

  __shared__ int ls[NT];
  int t = threadIdx.x;
  ls[t] = tsum;
  __syncthreads();
  for (int off = 1; off < NT; off <<= 1) {
    int u = (t >= off) ? ls[t - off] : 0;
    __syncthreads();
    ls[t] += u;
    __syncthreads();
  }
  int excl = offset + ls[t] - tsum;

  int4 o;
  o.x = excl;
  o.y = o.x + v.x;
  o.z = o.y + v.y;
  o.w = o.z + v.z;
  if (base + 3 < n) {
    *(int4*)&rp[base] = o;
    *(int4*)&cnt[base] = o;     // cursor = absolute row start
  } else {
    if (base + 0 < n) { rp[base + 0] = o.x; cnt[base + 0] = o.x; }
    if (base + 1 < n) { rp[base + 1] = o.y; cnt[base + 1] = o.y; }
    if (base + 2 < n) { rp[base + 2] = o.z; cnt[base + 2] = o.z; }
    if (base + 3 < n) { rp[base + 3] = o.w; cnt[base + 3] = o.w; }
  }
}

// ---------- fill split CSRs, 1 edge/thread, absolute cursors ----------
__global__ void fill2_k(const int* __restrict__ e_src, const int* __restrict__ e_dst, int E,
                        const int* __restrict__ c_src, const int* __restrict__ c_dst, int EC,
                        int* __restrict__ cur_c, int* __restrict__ csr_c,
                        int* __restrict__ cur_t, int* __restrict__ csr_t) {
  int i = blockIdx.x * NT + threadIdx.x;
  if (i < E) {
    csr_c[atomicAdd(&cur_c[e_dst[i]], 1)] = e_src[i];
  } else if (i < E + EC) {
    int j = i - E;
    csr_t[atomicAdd(&cur_t[c_dst[j]], 1)] = c_src[j];
  }
}

// ---------- per-edge weights for both CSRs ----------
__global__ void wv2_k(const int* __restrict__ csr_c, int E,
                      const int* __restrict__ csr_t, int EC,
                      const float* __restrict__ dc, const float* __restrict__ dt,
                      float* __restrict__ wv_c, float* __restrict__ wv_t) {
  int i = blockIdx.x * NT + threadIdx.x;
  if (i < E) wv_c[i] = dc[csr_c[i]];
  else if (i < E + EC) { int j = i - E; wv_t[j] = dt[csr_t[j]]; }
}

// ---------- x fp32 -> bf16 ----------
__global__ void convx_k(const float* __restrict__ x, ushort* __restrict__ xh, int total4) {
  int i = blockIdx.x * NT + threadIdx.x;
  if (i < total4) {
    float4 v = ((const float4*)x)[i];
    ushort4 o;
    o.x = f2bf(v.x); o.y = f2bf(v.y); o.z = f2bf(v.z); o.w = f2bf(v.w);
    ((ushort4*)xh)[i] = o;
  }
}

// ---------- W fp32 [l][k][c] -> bf16 transposed wT[l][c][k] ----------
__global__ void convw_k(const float* __restrict__ Wc, const float* __restrict__ Wt,
                        ushort* __restrict__ wT) {
  int gid = blockIdx.x * NT + threadIdx.x;
  int l = gid >> 14, rem = gid & 16383;
  int c = rem >> 7, k = rem & 127;
  const float* W = (l < 4) ? (Wc + (size_t)l * 16384) : (Wt + (size_t)(l - 4) * 16384);
  wT[gid] = f2bf(W[k * DFEAT + c]);
}

// ---------- single-graph CSR walk, chunk-16 issue, precomputed weights ----------
__device__ inline void walk16(const ushort* __restrict__ xh,
                              const int* __restrict__ cs, const float* __restrict__ wv,
                              int s0, int deg, int lane, int c4,
                              float& a0, float& a1, float& a2, float& a3) {
  for (int p = 0; p < deg; p += 32) {
    int rem = deg - p;                     // > 0
    int mm = min(32, rem);
    int idx = s0 + p + min(lane, rem - 1); // clamped: always valid edge slot
    int sv = cs[idx];
    float wl = wv[idx];                    // parallel with cs load
    float ws = (lane < mm) ? wl : 0.f;
    for (int k = 0; k < mm; k += 16) {
      int s[16]; float w[16];
#pragma unroll
      for (int j = 0; j < 16; j++) {
        s[j] = __shfl(sv, k + j, 32);
        w[j] = __shfl(ws, k + j, 32);
      }
      uint2 r[16];
#pragma unroll
      for (int j = 0; j < 16; j++) r[j] = *(const uint2*)&xh[(size_t)s[j] * DFEAT + c4];
#pragma unroll
      for (int j = 0; j < 16; j++) {
        float e0 = __uint_as_float(r[j].x << 16);
        float e1 = __uint_as_float(r[j].x & 0xffff0000u);
        float e2 = __uint_as_float(r[j].y << 16);
        float e3 = __uint_as_float(r[j].y & 0xffff0000u);
        a0 = fmaf(w[j], e0, a0); a1 = fmaf(w[j], e1, a1);
        a2 = fmaf(w[j], e2, a2); a3 = fmaf(w[j], e3, a3);
      }
    }
  }
}

// ---------- FUSED aggregate + dual-GEMM, M=16 tile, 512 threads ----------
// Phase 1: 16 groups x 32 lanes, ONE node per group (full gather TLP preserved)
//          -> LDS A-panel Ag[16][256] bf16 (conv k 0..127 | ctrl k 128..255),
//          XOR-swizzled by row for conflict-free phase-2 ds_read_b128.
// Phase 2: 8 waves, wave w computes out[16 rows][w*16..w*16+16), K=256; W-fragments
//          streamed from L2-resident wT; bias+relu fused; verified gemmf D-layout.
// Activations ping-pong between xhA/xhB across layers.
__global__ __launch_bounds__(512, 4) void aggemm16_k(
    const ushort* __restrict__ xin,
    const int* __restrict__ rp_c, const int* __restrict__ cs_c, const float* __restrict__ wv_c,
    const int* __restrict__ rp_t, const int* __restrict__ cs_t, const float* __restrict__ wv_t,
    const float* __restrict__ dc_, const float* __restrict__ dt_,
    const ushort* __restrict__ wTc, const ushort* __restrict__ wTt,
    const float* __restrict__ bc, const float* __restrict__ bt,
    float* __restrict__ outf, ushort* __restrict__ outh, int n, int last) {
  __shared__ __align__(16) ushort Ag[16 * 256];   // 8 KB
  __shared__ float bias[DFEAT];
  int tid = threadIdx.x;
  int base = blockIdx.x * 16;

  if (tid < DFEAT) bias[tid] = bc[tid] + bt[tid];

  // ---- phase 1: gather (1 node per 32-lane group) ----
  int grp = tid >> 5, lane = tid & 31, c4 = lane << 2;
  int node = base + grp;
  float a0 = 0.f, a1 = 0.f, a2 = 0.f, a3 = 0.f;
  float b0 = 0.f, b1 = 0.f, b2 = 0.f, b3 = 0.f;
  if (node < n) {
    float dc = dc_[node], dt = dt_[node];
    uint2 sv0 = *(const uint2*)&xin[(size_t)node * DFEAT + c4];
    float x0 = __uint_as_float(sv0.x << 16);
    float x1 = __uint_as_float(sv0.x & 0xffff0000u);
    float x2 = __uint_as_float(sv0.y << 16);
    float x3 = __uint_as_float(sv0.y & 0xffff0000u);
    a0 = dc * x0; a1 = dc * x1; a2 = dc * x2; a3 = dc * x3;
    b0 = dt * x0; b1 = dt * x1; b2 = dt * x2; b3 = dt * x3;

    int s0 = rp_c[node], d0 = rp_c[node + 1] - s0;
    walk16(xin, cs_c, wv_c, s0, d0, lane, c4, a0, a1, a2, a3);
    int s1 = rp_t[node], d1 = rp_t[node + 1] - s1;
    walk16(xin, cs_t, wv_t, s1, d1, lane, c4, b0, b1, b2, b3);

    a0 *= dc; a1 *= dc; a2 *= dc; a3 *= dc;
    b0 *= dt; b1 *= dt; b2 *= dt; b3 *= dt;
  }
  int swz = (grp & 7) << 3;                 // ushort-granule XOR within 128-col half
  ushort4 ha, hb;
  ha.x = f2bf(a0); ha.y = f2bf(a1); ha.z = f2bf(a2); ha.w = f2bf(a3);
  hb.x = f2bf(b0); hb.y = f2bf(b1); hb.z = f2bf(b2); hb.w = f2bf(b3);
  *(ushort4*)&Ag[grp * 256 + ((lane * 4) ^ swz)] = ha;          // conv half
  *(ushort4*)&Ag[grp * 256 + 128 + ((lane * 4) ^ swz)] = hb;    // ctrl half
  __syncthreads();

  // ---- phase 2: out[16][128] = Ag[16][256] @ [Wc;Wt], bias+relu ----
  int wave = tid >> 6, l64 = tid & 63;
  int m = l64 & 15, q = l64 >> 4;
  int rswz = (m & 7) << 3;

  f32x4 acc = {0.f, 0.f, 0.f, 0.f};
#pragma unroll
  for (int ks = 0; ks < 8; ks++) {
    int kb = ks * 32;                        // 0..255 across conv|ctrl halves
    const ushort* wTh = (ks < 4) ? wTc : wTt;
    int krel = kb & 127;
    union { uint4 u; s8v s; } uB, uW;
    uB.u = *(const uint4*)&Ag[m * 256 + ((kb + q * 8) ^ rswz)];
    uW.u = *(const uint4*)&wTh[(size_t)(wave * 16 + m) * DFEAT + krel + q * 8];
    acc = __builtin_amdgcn_mfma_f32_16x16x32_bf16(uW.s, uB.s, acc, 0, 0, 0);
  }

  // D layout: lane holds out[base + m][wave*16 + q*4 + r]
  int orow = base + m;
  if (orow < n) {
    int col = wave * 16 + q * 4;
    float4 bv = *(const float4*)&bias[col];
    float o0 = acc[0] + bv.x, o1 = acc[1] + bv.y;
    float o2 = acc[2] + bv.z, o3 = acc[3] + bv.w;
    if (last) {
      *(float4*)&outf[(size_t)orow * DFEAT + col] = make_float4(o0, o1, o2, o3);
    } else {
      ushort4 h;
      h.x = f2bf(fmaxf(o0, 0.f));
      h.y = f2bf(fmaxf(o1, 0.f));
      h.z = f2bf(fmaxf(o2, 0.f));
      h.w = f2bf(fmaxf(o3, 0.f));
      *(ushort4*)&outh[(size_t)orow * DFEAT + col] = h;
    }
  }
}

extern "C" void kernel_launch(void* const* d_in, const int* in_sizes, int n_in,
                              void* d_out, int out_size, void* d_ws, size_t ws_size,
                              hipStream_t stream) {
  const float* x0 = (const float*)d_in[0];
  const int*   ei = (const int*)d_in[1];
  const int*   ci = (const int*)d_in[2];
  const float* Wc = (const float*)d_in[3];
  const float* bc = (const float*)d_in[4];
  const float* Wt = (const float*)d_in[5];
  const float* bt = (const float*)d_in[6];
  float* out = (float*)d_out;

  int n  = in_sizes[0] / DFEAT;     // 100000
  int E  = in_sizes[1] / 2;         // 600000
  int EC = in_sizes[2] / 2;         // 200000

  const int* e_src = ei;
  const int* e_dst = ei + E;
  const int* c_src = ci;
  const int* c_dst = ci + EC;

  char* p = (char*)d_ws;
  ushort* xhA = (ushort*)p; p += (size_t)n * DFEAT * 2;
  ushort* xhB = (ushort*)p; p += (size_t)n * DFEAT * 2;
  ushort* wT  = (ushort*)p; p += (size_t)8 * DFEAT * DFEAT * 2;
  float* dinv_c = (float*)p; p += (size_t)n * 4;
  float* dinv_t = (float*)p; p += (size_t)n * 4;
  int* cnt_c = (int*)p; p += (size_t)n * 4;     // histogram -> cursor
  int* cnt_t = (int*)p; p += (size_t)n * 4;
  int* rp_c  = (int*)p; p += (size_t)(n + 1) * 4;
  int* rp_t  = (int*)p; p += (size_t)(n + 1) * 4;
  int* csr_c = (int*)p; p += (size_t)E * 4;
  int* csr_t = (int*)p; p += (size_t)EC * 4;
  float* wv_c = (float*)p; p += (size_t)E * 4;
  float* wv_t = (float*)p; p += (size_t)EC * 4;
  int* bsum  = (int*)p;

  int nb_n     = (n + NT - 1) / NT;
  int nb_scan  = (n + SCAN_ELEMS - 1) / SCAN_ELEMS;
  int nb_fused = (n + 15) / 16;

  // ---- build split CSRs + dinv + per-edge weights once per launch ----
  zero_k<<<(2 * n + NT - 1) / NT, NT, 0, stream>>>(cnt_c, 2 * n);
  hist2_k<<<(E + EC + NT - 1) / NT, NT, 0, stream>>>(e_dst, E, c_dst, EC, cnt_c, cnt_t);
  dinv2_k<<<nb_n, NT, 0, stream>>>(cnt_c, cnt_t, dinv_c, dinv_t, n);
  scan_partial_k<<<2 * nb_scan, NT, 0, stream>>>(cnt_c, cnt_t, n, bsum, nb_scan);
  scan_offsets_k<<<2, NT, 0, stream>>>(bsum, nb_scan, nb_scan, rp_c, rp_t, n);
  scan_final_k<<<2 * nb_scan, NT, 0, stream>>>(cnt_c, cnt_t, n, bsum, nb_scan, rp_c, rp_t);
  fill2_k<<<(E + EC + NT - 1) / NT, NT, 0, stream>>>(e_src, e_dst, E, c_src, c_dst, EC,
                                                     cnt_c, csr_c, cnt_t, csr_t);
  wv2_k<<<(E + EC + NT - 1) / NT, NT, 0, stream>>>(csr_c, E, csr_t, EC,
                                                   dinv_c, dinv_t, wv_c, wv_t);

  // ---- bf16 conversions ----
  convx_k<<<(n * 32 + NT - 1) / NT, NT, 0, stream>>>(x0, xhA, n * 32);
  convw_k<<<(8 * DFEAT * DFEAT) / NT, NT, 0, stream>>>(Wc, Wt, wT);

  // ---- layers: fused gather+GEMM (M=16), ping-ponged activations ----
  ushort* bin = xhA;
  ushort* bout = xhB;
  for (int i = 0; i < 4; i++) {
    aggemm16_k<<<nb_fused, 512, 0, stream>>>(bin,
                                             rp_c, csr_c, wv_c,
                                             rp_t, csr_t, wv_t,
                                             dinv_c, dinv_t,
                                             wT + (size_t)i * DFEAT * DFEAT,
                                             wT + (size_t)(4 + i) * DFEAT * DFEAT,
                                             bc + i * DFEAT, bt + i * DFEAT,
                                             out, bout, n, (i == 3) ? 1 : 0);
    ushort* t = bin; bin = bout; bout = t;
  }
}

// Round 8
// 554.455 us; speedup vs baseline: 1.2174x; 1.2174x over previous
//
#include <hip/hip_runtime.h>
#include <cstdint>
#include <cstddef>

#define NT 256
#define DFEAT 128
#define SCAN_ELEMS 1024
#define GEMM_ROWS 128    // rows per gemm block (4 waves x 32 rows)
#define BPAD 136         // padded LDS k-stride (ushorts) for W^T tiles
#define FCE 2048         // edges per fillx chunk

typedef __attribute__((ext_vector_type(8))) short s8v;
typedef __attribute__((ext_vector_type(4))) float f32x4;

__device__ inline ushort f2bf(float f) {           // RNE fp32 -> bf16
  uint32_t u = __float_as_uint(f);
  u += 0x7fffu + ((u >> 16) & 1u);
  return (ushort)(u >> 16);
}

// ---------- megapre: hist (atomics) + convx (stream) + convw, one dispatch ----------
__global__ void megapre_k(const int* __restrict__ e_dst, int E,
                          const int* __restrict__ c_dst, int EC,
                          int* __restrict__ cnt_c, int* __restrict__ cnt_t,
                          const float* __restrict__ x, ushort* __restrict__ xh, int total4,
                          const float* __restrict__ Wc, const float* __restrict__ Wt,
                          ushort* __restrict__ wT, int nbh, int nbx) {
  int b = blockIdx.x;
  if (b < nbh) {                       // ---- histogram section ----
    int i = b * NT + threadIdx.x;
    if (i < E) atomicAdd(&cnt_c[e_dst[i]], 1);
    else if (i < E + EC) atomicAdd(&cnt_t[c_dst[i - E]], 1);
  } else if (b < nbh + nbx) {          // ---- convx section ----
    int i = (b - nbh) * NT + threadIdx.x;
    if (i < total4) {
      float4 v = ((const float4*)x)[i];
      ushort4 o;
      o.x = f2bf(v.x); o.y = f2bf(v.y); o.z = f2bf(v.z); o.w = f2bf(v.w);
      ((ushort4*)xh)[i] = o;
    }
  } else {                             // ---- convw section ----
    int gid = (b - nbh - nbx) * NT + threadIdx.x;   // 0 .. 8*128*128
    int l = gid >> 14, rem = gid & 16383;
    int c = rem >> 7, k = rem & 127;
    const float* W = (l < 4) ? (Wc + (size_t)l * 16384) : (Wt + (size_t)(l - 4) * 16384);
    wT[gid] = f2bf(W[k * DFEAT + c]);
  }
}

// ---------- scan pass A (split) + fused dinv ----------
__global__ __launch_bounds__(NT) void scan_partial_d(
    const int* __restrict__ cnt_c, const int* __restrict__ cnt_t, int n,
    int* __restrict__ bsum, int nb_c,
    float* __restrict__ dc, float* __restrict__ dt) {
  int isT = blockIdx.x >= nb_c;
  const int* cnt = isT ? cnt_t : cnt_c;
  float* dv = isT ? dt : dc;
  int b = isT ? blockIdx.x - nb_c : blockIdx.x;
  int base = b * SCAN_ELEMS + threadIdx.x * 4;

  int s = 0;
  if (base + 3 < n) {
    int4 v = *(const int4*)&cnt[base];
    s = v.x + v.y + v.z + v.w;
    float4 d;
    d.x = rsqrtf((float)(v.x + 1));
    d.y = rsqrtf((float)(v.y + 1));
    d.z = rsqrtf((float)(v.z + 1));
    d.w = rsqrtf((float)(v.w + 1));
    *(float4*)&dv[base] = d;
  } else {
    for (int j = 0; j < 4; j++)
      if (base + j < n) { int v = cnt[base + j]; s += v; dv[base + j] = rsqrtf((float)(v + 1)); }
  }
  for (int off = 32; off > 0; off >>= 1) s += __shfl_down(s, off, 64);
  __shared__ int ws[4];
  int lane = threadIdx.x & 63, w = threadIdx.x >> 6;
  if (lane == 0) ws[w] = s;
  __syncthreads();
  if (threadIdx.x == 0) bsum[blockIdx.x] = ws[0] + ws[1] + ws[2] + ws[3];
}

// ---------- scan pass B ----------
__global__ __launch_bounds__(NT) void scan_offsets_k(
    int* __restrict__ bsum, int nb_c, int nb_t,
    int* __restrict__ rp_c, int* __restrict__ rp_t, int n) {
  int seg_off = (blockIdx.x == 0) ? 0 : nb_c;
  int nb = (blockIdx.x == 0) ? nb_c : nb_t;
  int* rp = (blockIdx.x == 0) ? rp_c : rp_t;

  __shared__ int ls[NT];
  int t = threadIdx.x;
  int v = (t < nb) ? bsum[seg_off + t] : 0;
  ls[t] = v;
  __syncthreads();
  for (int off = 1; off < NT; off <<= 1) {
    int u = (t >= off) ? ls[t - off] : 0;
    __syncthreads();
    ls[t] += u;
    __syncthreads();
  }
  if (t < nb) bsum[seg_off + t] = ls[t] - v;
  if (t == nb - 1) rp[n] = ls[t];
}

// ---------- scan pass C: rowptr out; cursor array seeded with row offsets ----------
__global__ __launch_bounds__(NT) void scan_final_k(
    int* __restrict__ cnt_c, int* __restrict__ cnt_t, int n,
    const int* __restrict__ bsum, int nb_c,
    int* __restrict__ rp_c, int* __restrict__ rp_t) {
  int isT = blockIdx.x >= nb_c;
  int* cnt = isT ? cnt_t : cnt_c;
  int* rp = isT ? rp_t : rp_c;
  int b = isT ? blockIdx.x - nb_c : blockIdx.x;
  int offset = bsum[blockIdx.x];
  int base = b * SCAN_ELEMS + threadIdx.x * 4;

  int4 v = make_int4(0, 0, 0, 0);
  if (base + 3 < n) v = *(const int4*)&cnt[base];
  else { if (base + 0 < n) v.x = cnt[base + 0];
         if (base + 1 < n) v.y = cnt[base + 1];
         if (base + 2 < n) v.z = cnt[base + 2];
         if (base + 3 < n) v.w = cnt[base + 3]; }
  int tsum = v.x + v.y + v.z + v.w;

  __shared__ int ls[NT];
  int t = threadIdx.x;
  ls[t] = tsum;
  __syncthreads();
  for (int off = 1; off < NT; off <<= 1) {
    int u = (t >= off) ? ls[t - off] : 0;
    __syncthreads();
    ls[t] += u;
    __syncthreads();
  }
  int excl = offset + ls[t] - tsum;

  int4 o;
  o.x = excl;
  o.y = o.x + v.x;
  o.z = o.y + v.y;
  o.w = o.z + v.z;
  if (base + 3 < n) {
    *(int4*)&rp[base] = o;
    *(int4*)&cnt[base] = o;     // cursor = absolute row start
  } else {
    if (base + 0 < n) { rp[base + 0] = o.x; cnt[base + 0] = o.x; }
    if (base + 1 < n) { rp[base + 1] = o.y; cnt[base + 1] = o.y; }
    if (base + 2 < n) { rp[base + 2] = o.z; cnt[base + 2] = o.z; }
    if (base + 3 < n) { rp[base + 3] = o.w; cnt[base + 3] = o.w; }
  }
}

// ---------- XCD-local fill: block b -> edge chunk b/8, dst range b%8 ----------
// Consecutive blockIdx round-robin across the 8 XCDs, so range r is written only
// from XCD r: csr slice (~0.4MB) stays in that XCD's L2, written back once.
// If the mapping assumption fails, correctness is unaffected (just slower).
__global__ void fillx_k(const int* __restrict__ e_src, const int* __restrict__ e_dst, int E,
                        const int* __restrict__ c_src, const int* __restrict__ c_dst, int EC,
                        int* __restrict__ cur_c, int* __restrict__ csr_c,
                        int* __restrict__ cur_t, int* __restrict__ csr_t, int n) {
  int slot = blockIdx.x & 7;
  int chunk = blockIdx.x >> 3;
  int lo = (int)(((long long)slot * n) >> 3);
  int hi = (int)(((long long)(slot + 1) * n) >> 3);
  int start = chunk * FCE;
  int end = min(start + FCE, E + EC);
  for (int i = start + (int)threadIdx.x; i < end; i += NT) {
    if (i < E) {
      int d = e_dst[i];
      if (d >= lo && d < hi) csr_c[atomicAdd(&cur_c[d], 1)] = e_src[i];
    } else {
      int j = i - E;
      int d = c_dst[j];
      if (d >= lo && d < hi) csr_t[atomicAdd(&cur_t[d], 1)] = c_src[j];
    }
  }
}

// ---------- per-edge weights for both CSRs ----------
__global__ void wv2_k(const int* __restrict__ csr_c, int E,
                      const int* __restrict__ csr_t, int EC,
                      const float* __restrict__ dc, const float* __restrict__ dt,
                      float* __restrict__ wv_c, float* __restrict__ wv_t) {
  int i = blockIdx.x * NT + threadIdx.x;
  if (i < E) wv_c[i] = dc[csr_c[i]];
  else if (i < E + EC) { int j = i - E; wv_t[j] = dt[csr_t[j]]; }
}

// ---------- single-graph CSR walk, chunk-16 issue, precomputed weights ----------
__device__ inline void walk16(const ushort* __restrict__ xh,
                              const int* __restrict__ cs, const float* __restrict__ wv,
                              int s0, int deg, int lane, int c4,
                              float& a0, float& a1, float& a2, float& a3) {
  for (int p = 0; p < deg; p += 32) {
    int rem = deg - p;                     // > 0
    int mm = min(32, rem);
    int idx = s0 + p + min(lane, rem - 1); // clamped: always valid edge slot
    int sv = cs[idx];
    float wl = wv[idx];                    // parallel with cs load
    float ws = (lane < mm) ? wl : 0.f;
    for (int k = 0; k < mm; k += 16) {
      int s[16]; float w[16];
#pragma unroll
      for (int j = 0; j < 16; j++) {
        s[j] = __shfl(sv, k + j, 32);
        w[j] = __shfl(ws, k + j, 32);
      }
      uint2 r[16];
#pragma unroll
      for (int j = 0; j < 16; j++) r[j] = *(const uint2*)&xh[(size_t)s[j] * DFEAT + c4];
#pragma unroll
      for (int j = 0; j < 16; j++) {
        float e0 = __uint_as_float(r[j].x << 16);
        float e1 = __uint_as_float(r[j].x & 0xffff0000u);
        float e2 = __uint_as_float(r[j].y << 16);
        float e3 = __uint_as_float(r[j].y & 0xffff0000u);
        a0 = fmaf(w[j], e0, a0); a1 = fmaf(w[j], e1, a1);
        a2 = fmaf(w[j], e2, a2); a3 = fmaf(w[j], e3, a3);
      }
    }
  }
}

// ---------- split-CSR aggregate: 1 node per 32-lane group, both walks ----------
__global__ __launch_bounds__(256) void aggregate7_k(
    const ushort* __restrict__ xh,
    const int* __restrict__ rp_c, const int* __restrict__ cs_c, const float* __restrict__ wv_c,
    const int* __restrict__ rp_t, const int* __restrict__ cs_t, const float* __restrict__ wv_t,
    const float* __restrict__ dc_, const float* __restrict__ dt_,
    ushort* __restrict__ aggc, ushort* __restrict__ aggt, int n) {
  int node = blockIdx.x * 8 + (threadIdx.x >> 5);
  if (node >= n) return;
  int lane = threadIdx.x & 31;
  int c4 = lane << 2;

  float dc = dc_[node], dt = dt_[node];
  uint2 sv0 = *(const uint2*)&xh[(size_t)node * DFEAT + c4];
  float x0 = __uint_as_float(sv0.x << 16);
  float x1 = __uint_as_float(sv0.x & 0xffff0000u);
  float x2 = __uint_as_float(sv0.y << 16);
  float x3 = __uint_as_float(sv0.y & 0xffff0000u);

  float a0 = dc * x0, a1 = dc * x1, a2 = dc * x2, a3 = dc * x3;   // conv acc
  float b0 = dt * x0, b1 = dt * x1, b2 = dt * x2, b3 = dt * x3;   // ctrl acc

  int s0 = rp_c[node], d0 = rp_c[node + 1] - s0;
  walk16(xh, cs_c, wv_c, s0, d0, lane, c4, a0, a1, a2, a3);
  int s1 = rp_t[node], d1 = rp_t[node + 1] - s1;
  walk16(xh, cs_t, wv_t, s1, d1, lane, c4, b0, b1, b2, b3);

  ushort4 ha, hb;
  ha.x = f2bf(dc * a0); ha.y = f2bf(dc * a1); ha.z = f2bf(dc * a2); ha.w = f2bf(dc * a3);
  hb.x = f2bf(dt * b0); hb.y = f2bf(dt * b1); hb.z = f2bf(dt * b2); hb.w = f2bf(dt * b3);
  *(ushort4*)&aggc[(size_t)node * DFEAT + c4] = ha;
  *(ushort4*)&aggt[(size_t)node * DFEAT + c4] = hb;
}

// ---------- fused K=256 GEMM (R3 best-measured variant): prefetch + 2-tile LDS ----------
// Operand-swapped mfma -> packed ushort4/float4 row-major stores.
__global__ __launch_bounds__(256, 2) void gemmf_k(
    const ushort* __restrict__ ac, const ushort* __restrict__ at,
    const ushort* __restrict__ wTc, const ushort* __restrict__ wTt,
    const float* __restrict__ bc, const float* __restrict__ bt,
    float* __restrict__ outf, ushort* __restrict__ outh, int n, int last) {
  __shared__ __align__(16) ushort Bs[2][DFEAT * BPAD];
  __shared__ float bias[DFEAT];
  int tid = threadIdx.x;

#pragma unroll
  for (int it = 0; it < 8; it++) {
    int idx = tid + it * NT;          // 0..2047: 128 rows x 16 uint4
    int c = idx >> 4, i = idx & 15;
    *(uint4*)&Bs[0][c * BPAD + i * 8] = *(const uint4*)&wTc[c * DFEAT + i * 8];
    *(uint4*)&Bs[1][c * BPAD + i * 8] = *(const uint4*)&wTt[c * DFEAT + i * 8];
  }
  if (tid < DFEAT) bias[tid] = bc[tid] + bt[tid];
  __syncthreads();

  int wave = tid >> 6;
  int lane = tid & 63;
  int m = lane & 15;
  int q = lane >> 4;
  int row0 = blockIdx.x * GEMM_ROWS + wave * 32;
  int rA = min(row0 + m, n - 1);
  int rB = min(row0 + 16 + m, n - 1);

  uint4 fA[8], fB[8];
#pragma unroll
  for (int ks = 0; ks < 8; ks++) {                 // K=256: 0..3 conv-half, 4..7 ctrl-half
    const ushort* A = (ks < 4) ? ac : at;
    int ko = (ks & 3) * 32 + q * 8;
    fA[ks] = *(const uint4*)&A[(size_t)rA * DFEAT + ko];
    fB[ks] = *(const uint4*)&A[(size_t)rB * DFEAT + ko];
  }

  f32x4 zero4 = {0.f, 0.f, 0.f, 0.f};
  f32x4 acc0[8], acc1[8];
#pragma unroll
  for (int i = 0; i < 8; i++) { acc0[i] = zero4; acc1[i] = zero4; }

#pragma unroll
  for (int ks = 0; ks < 8; ks++) {
    int ko = (ks & 3) * 32 + q * 8;
    union { uint4 u; s8v s; } uA, uB; uA.u = fA[ks]; uB.u = fB[ks];
#pragma unroll
    for (int c8 = 0; c8 < 8; c8++) {
      s8v bf = *(const s8v*)&Bs[ks >> 2][(c8 * 16 + m) * BPAD + ko];
      acc0[c8] = __builtin_amdgcn_mfma_f32_16x16x32_bf16(bf, uA.s, acc0[c8], 0, 0, 0);
      acc1[c8] = __builtin_amdgcn_mfma_f32_16x16x32_bf16(bf, uB.s, acc1[c8], 0, 0, 0);
    }
  }

#pragma unroll
  for (int sub = 0; sub < 2; sub++) {
    int orow = row0 + sub * 16 + m;
    if (orow < n) {
#pragma unroll
      for (int c8 = 0; c8 < 8; c8++) {
        f32x4 a = sub ? acc1[c8] : acc0[c8];
        int col = c8 * 16 + q * 4;
        float4 bv = *(const float4*)&bias[col];
        float o0 = a[0] + bv.x, o1 = a[1] + bv.y, o2 = a[2] + bv.z, o3 = a[3] + bv.w;
        if (last) {
          *(float4*)&outf[(size_t)orow * DFEAT + col] = make_float4(o0, o1, o2, o3);
        } else {
          ushort4 h;
          h.x = f2bf(fmaxf(o0, 0.f));
          h.y = f2bf(fmaxf(o1, 0.f));
          h.z = f2bf(fmaxf(o2, 0.f));
          h.w = f2bf(fmaxf(o3, 0.f));
          *(ushort4*)&outh[(size_t)orow * DFEAT + col] = h;
        }
      }
    }
  }
}

extern "C" void kernel_launch(void* const* d_in, const int* in_sizes, int n_in,
                              void* d_out, int out_size, void* d_ws, size_t ws_size,
                              hipStream_t stream) {
  const float* x0 = (const float*)d_in[0];
  const int*   ei = (const int*)d_in[1];
  const int*   ci = (const int*)d_in[2];
  const float* Wc = (const float*)d_in[3];
  const float* bc = (const float*)d_in[4];
  const float* Wt = (const float*)d_in[5];
  const float* bt = (const float*)d_in[6];
  float* out = (float*)d_out;

  int n  = in_sizes[0] / DFEAT;     // 100000
  int E  = in_sizes[1] / 2;         // 600000
  int EC = in_sizes[2] / 2;         // 200000
  int etot = E + EC;

  const int* e_src = ei;
  const int* e_dst = ei + E;
  const int* c_src = ci;
  const int* c_dst = ci + EC;

  char* p = (char*)d_ws;
  ushort* agg_c = (ushort*)p; p += (size_t)n * DFEAT * 2;
  ushort* agg_t = (ushort*)p; p += (size_t)n * DFEAT * 2;
  ushort* xh  = (ushort*)p; p += (size_t)n * DFEAT * 2;
  ushort* wT  = (ushort*)p; p += (size_t)8 * DFEAT * DFEAT * 2;
  float* dinv_c = (float*)p; p += (size_t)n * 4;
  float* dinv_t = (float*)p; p += (size_t)n * 4;
  int* cnt_c = (int*)p; p += (size_t)n * 4;     // histogram -> cursor
  int* cnt_t = (int*)p; p += (size_t)n * 4;
  int* rp_c  = (int*)p; p += (size_t)(n + 1) * 4;
  int* rp_t  = (int*)p; p += (size_t)(n + 1) * 4;
  int* csr_c = (int*)p; p += (size_t)E * 4;
  int* csr_t = (int*)p; p += (size_t)EC * 4;
  float* wv_c = (float*)p; p += (size_t)E * 4;
  float* wv_t = (float*)p; p += (size_t)EC * 4;
  int* bsum  = (int*)p;

  int nb_scan  = (n + SCAN_ELEMS - 1) / SCAN_ELEMS;
  int nb_gemm  = (n + GEMM_ROWS - 1) / GEMM_ROWS;
  int nb_node  = (n + 7) / 8;
  int nbh = (etot + NT - 1) / NT;               // hist section blocks
  int nbx = (n * 32 + NT - 1) / NT;             // convx section blocks
  int nbw = (8 * DFEAT * DFEAT) / NT;           // convw section blocks
  int nb_fillx = ((etot + FCE - 1) / FCE) * 8;

  // ---- build CSRs + dinv + weights; conversions overlapped in megapre ----
  hipMemsetAsync(cnt_c, 0, (size_t)2 * n * 4, stream);
  megapre_k<<<nbh + nbx + nbw, NT, 0, stream>>>(e_dst, E, c_dst, EC, cnt_c, cnt_t,
                                                x0, xh, n * 32, Wc, Wt, wT, nbh, nbx);
  scan_partial_d<<<2 * nb_scan, NT, 0, stream>>>(cnt_c, cnt_t, n, bsum, nb_scan,
                                                 dinv_c, dinv_t);
  scan_offsets_k<<<2, NT, 0, stream>>>(bsum, nb_scan, nb_scan, rp_c, rp_t, n);
  scan_final_k<<<2 * nb_scan, NT, 0, stream>>>(cnt_c, cnt_t, n, bsum, nb_scan, rp_c, rp_t);
  fillx_k<<<nb_fillx, NT, 0, stream>>>(e_src, e_dst, E, c_src, c_dst, EC,
                                       cnt_c, csr_c, cnt_t, csr_t, n);
  wv2_k<<<(etot + NT - 1) / NT, NT, 0, stream>>>(csr_c, E, csr_t, EC,
                                                 dinv_c, dinv_t, wv_c, wv_t);

  // ---- layers: split aggregate then fused K=256 GEMM (best measured combo) ----
  for (int i = 0; i < 4; i++) {
    aggregate7_k<<<nb_node, NT, 0, stream>>>(xh,
                                             rp_c, csr_c, wv_c,
                                             rp_t, csr_t, wv_t,
                                             dinv_c, dinv_t, agg_c, agg_t, n);
    gemmf_k<<<nb_gemm, NT, 0, stream>>>(agg_c, agg_t,
                                        wT + (size_t)i * DFEAT * DFEAT,
                                        wT + (size_t)(4 + i) * DFEAT * DFEAT,
                                        bc + i * DFEAT, bt + i * DFEAT,
                                        out, xh, n, (i == 3) ? 1 : 0);
  }
}

// Round 10
// 459.488 us; speedup vs baseline: 1.4690x; 1.2067x over previous
//
#include <hip/hip_runtime.h>
#include <cstdint>
#include <cstddef>

#define NT 256
#define DFEAT 128
#define SCAN_ELEMS 1024
#define GEMM_ROWS 128    // rows per gemm block (4 waves x 32 rows)
#define BPAD 136         // padded LDS k-stride (ushorts) for W^T tiles
#define CTRL_FLAG 0x40000000
#define SRC_MASK  0x3fffffff

typedef __attribute__((ext_vector_type(8))) short s8v;
typedef __attribute__((ext_vector_type(4))) float f32x4;
typedef __attribute__((ext_vector_type(2))) uint u32x2;   // nontemporal-compatible
typedef __attribute__((ext_vector_type(4))) uint u32x4;   // nontemporal-compatible

__device__ inline ushort f2bf(float f) {           // RNE fp32 -> bf16
  uint32_t u = __float_as_uint(f);
  u += 0x7fffu + ((u >> 16) & 1u);
  return (ushort)(u >> 16);
}

// ---------- megapre: hist (atomics) + convx (stream) + convw, one dispatch ----------
__global__ void megapre_k(const int* __restrict__ e_dst, int E,
                          const int* __restrict__ c_dst, int EC,
                          int* __restrict__ cnt_c, int* __restrict__ cnt_t,
                          const float* __restrict__ x, ushort* __restrict__ xh, int total4,
                          const float* __restrict__ Wc, const float* __restrict__ Wt,
                          ushort* __restrict__ wT, int nbh, int nbx) {
  int b = blockIdx.x;
  if (b < nbh) {                       // ---- histogram section ----
    int i = b * NT + threadIdx.x;
    if (i < E) atomicAdd(&cnt_c[e_dst[i]], 1);
    else if (i < E + EC) atomicAdd(&cnt_t[c_dst[i - E]], 1);
  } else if (b < nbh + nbx) {          // ---- convx section ----
    int i = (b - nbh) * NT + threadIdx.x;
    if (i < total4) {
      float4 v = ((const float4*)x)[i];
      ushort4 o;
      o.x = f2bf(v.x); o.y = f2bf(v.y); o.z = f2bf(v.z); o.w = f2bf(v.w);
      ((ushort4*)xh)[i] = o;
    }
  } else {                             // ---- convw section ----
    int gid = (b - nbh - nbx) * NT + threadIdx.x;   // 0 .. 8*128*128
    int l = gid >> 14, rem = gid & 16383;
    int c = rem >> 7, k = rem & 127;
    const float* W = (l < 4) ? (Wc + (size_t)l * 16384) : (Wt + (size_t)(l - 4) * 16384);
    wT[gid] = f2bf(W[k * DFEAT + c]);
  }
}

// ---------- merged scan pass A + fused dinv (dall[0..n)=conv, [n..2n)=ctrl) ----------
__global__ __launch_bounds__(NT) void scan_partial_md(
    const int* __restrict__ cnt_c, const int* __restrict__ cnt_t, int n,
    int* __restrict__ bsum, float* __restrict__ dall) {
  int base = blockIdx.x * SCAN_ELEMS + threadIdx.x * 4;
  int s = 0;
  if (base + 3 < n) {
    int4 a = *(const int4*)&cnt_c[base];
    int4 b = *(const int4*)&cnt_t[base];
    s = a.x + a.y + a.z + a.w + b.x + b.y + b.z + b.w;
    float4 da, db;
    da.x = rsqrtf((float)(a.x + 1)); da.y = rsqrtf((float)(a.y + 1));
    da.z = rsqrtf((float)(a.z + 1)); da.w = rsqrtf((float)(a.w + 1));
    db.x = rsqrtf((float)(b.x + 1)); db.y = rsqrtf((float)(b.y + 1));
    db.z = rsqrtf((float)(b.z + 1)); db.w = rsqrtf((float)(b.w + 1));
    *(float4*)&dall[base] = da;
    *(float4*)&dall[n + base] = db;
  } else {
    for (int j = 0; j < 4; j++)
      if (base + j < n) {
        int a = cnt_c[base + j], b = cnt_t[base + j];
        s += a + b;
        dall[base + j] = rsqrtf((float)(a + 1));
        dall[n + base + j] = rsqrtf((float)(b + 1));
      }
  }
  for (int off = 32; off > 0; off >>= 1) s += __shfl_down(s, off, 64);
  __shared__ int ws[4];
  int lane = threadIdx.x & 63, w = threadIdx.x >> 6;
  if (lane == 0) ws[w] = s;
  __syncthreads();
  if (threadIdx.x == 0) bsum[blockIdx.x] = ws[0] + ws[1] + ws[2] + ws[3];
}

// ---------- merged scan pass B ----------
__global__ __launch_bounds__(NT) void scan_offsets_m(
    int* __restrict__ bsum, int nb, int* __restrict__ rp, int n) {
  __shared__ int ls[NT];
  int t = threadIdx.x;
  int v = (t < nb) ? bsum[t] : 0;
  ls[t] = v;
  __syncthreads();
  for (int off = 1; off < NT; off <<= 1) {
    int u = (t >= off) ? ls[t - off] : 0;
    __syncthreads();
    ls[t] += u;
    __syncthreads();
  }
  if (t < nb) bsum[t] = ls[t] - v;
  if (t == nb - 1) rp[n] = ls[t];
}

// ---------- merged scan pass C: rowptr + absolute cursor in cnt_c ----------
__global__ __launch_bounds__(NT) void scan_final_m(
    int* __restrict__ cnt_c, const int* __restrict__ cnt_t, int n,
    const int* __restrict__ bsum, int* __restrict__ rp) {
  int offset = bsum[blockIdx.x];
  int base = blockIdx.x * SCAN_ELEMS + threadIdx.x * 4;

  int4 v = make_int4(0, 0, 0, 0);
  if (base + 3 < n) {
    int4 a = *(const int4*)&cnt_c[base];
    int4 b = *(const int4*)&cnt_t[base];
    v = make_int4(a.x + b.x, a.y + b.y, a.z + b.z, a.w + b.w);
  } else {
    if (base + 0 < n) v.x = cnt_c[base + 0] + cnt_t[base + 0];
    if (base + 1 < n) v.y = cnt_c[base + 1] + cnt_t[base + 1];
    if (base + 2 < n) v.z = cnt_c[base + 2] + cnt_t[base + 2];
    if (base + 3 < n) v.w = cnt_c[base + 3] + cnt_t[base + 3];
  }
  int tsum = v.x + v.y + v.z + v.w;

  __shared__ int ls[NT];
  int t = threadIdx.x;
  ls[t] = tsum;
  __syncthreads();
  for (int off = 1; off < NT; off <<= 1) {
    int u = (t >= off) ? ls[t - off] : 0;
    __syncthreads();
    ls[t] += u;
    __syncthreads();
  }
  int excl = offset + ls[t] - tsum;

  int4 o;
  o.x = excl;
  o.y = o.x + v.x;
  o.z = o.y + v.y;
  o.w = o.z + v.z;
  if (base + 3 < n) {
    *(int4*)&rp[base] = o;
    *(int4*)&cnt_c[base] = o;   // cursor = absolute row start
  } else {
    if (base + 0 < n) { rp[base + 0] = o.x; cnt_c[base + 0] = o.x; }
    if (base + 1 < n) { rp[base + 1] = o.y; cnt_c[base + 1] = o.y; }
    if (base + 2 < n) { rp[base + 2] = o.z; cnt_c[base + 2] = o.z; }
    if (base + 3 < n) { rp[base + 3] = o.w; cnt_c[base + 3] = o.w; }
  }
}

// ---------- fill merged CSR, 1 edge/thread, absolute cursor ----------
__global__ void fill_k(const int* __restrict__ e_src, const int* __restrict__ e_dst, int E,
                       const int* __restrict__ c_src, const int* __restrict__ c_dst, int EC,
                       int* __restrict__ cur, int* __restrict__ csr) {
  int i = blockIdx.x * NT + threadIdx.x;
  if (i < E) {
    csr[atomicAdd(&cur[e_dst[i]], 1)] = e_src[i];
  } else if (i < E + EC) {
    int j = i - E;
    csr[atomicAdd(&cur[c_dst[j]], 1)] = c_src[j] | CTRL_FLAG;
  }
}

// ---------- per-edge signed weight: wv[e] = (+/-) dinv[src] (ctrl = negative) ----------
__global__ void wv_k(const int* __restrict__ csr, const float* __restrict__ dall,
                     float* __restrict__ wv, int etot, int n) {
  int i = blockIdx.x * NT + threadIdx.x;
  if (i < etot) {
    int v = csr[i];
    int s = v & SRC_MASK;
    int f = (v >> 30) & 1;
    float w = dall[s + f * n];
    wv[i] = f ? -w : w;
  }
}

// ---------- merged-CSR aggregate: 1 node/group, chunk-8, signed wv, NT stores ----------
// Chunk-8 minimizes clamp-dup overissue at mean merged degree ~8 (R8 lesson: chunk-16
// on low-degree walks overissues up to 8x). Non-temporal agg stores keep the one-shot
// 51.2MB stream out of L2 so the gather's xh working set stays resident.
__global__ __launch_bounds__(256) void aggregate8_k(
    const ushort* __restrict__ xh,
    const int* __restrict__ rp, const int* __restrict__ cs, const float* __restrict__ wv,
    const float* __restrict__ dall,
    ushort* __restrict__ aggc, ushort* __restrict__ aggt, int n) {
  int node = blockIdx.x * 8 + (threadIdx.x >> 5);
  if (node >= n) return;
  int lane = threadIdx.x & 31;
  int c4 = lane << 2;

  float dc = dall[node], dt = dall[n + node];
  uint2 sv0 = *(const uint2*)&xh[(size_t)node * DFEAT + c4];
  float x0 = __uint_as_float(sv0.x << 16);
  float x1 = __uint_as_float(sv0.x & 0xffff0000u);
  float x2 = __uint_as_float(sv0.y << 16);
  float x3 = __uint_as_float(sv0.y & 0xffff0000u);

  float a0 = dc * x0, a1 = dc * x1, a2 = dc * x2, a3 = dc * x3;   // conv acc
  float b0 = dt * x0, b1 = dt * x1, b2 = dt * x2, b3 = dt * x3;   // ctrl acc

  int s0 = rp[node], deg = rp[node + 1] - s0;
  for (int p = 0; p < deg; p += 32) {
    int rem = deg - p;                     // > 0
    int mm = min(32, rem);
    int idx = s0 + p + min(lane, rem - 1); // clamped: always valid edge slot
    int sv = cs[idx] & SRC_MASK;
    float wl = wv[idx];                    // parallel with cs load
    float ws = (lane < mm) ? wl : 0.f;
    for (int k = 0; k < mm; k += 8) {
      int s[8]; float w[8];
#pragma unroll
      for (int j = 0; j < 8; j++) {
        s[j] = __shfl(sv, k + j, 32);
        w[j] = __shfl(ws, k + j, 32);
      }
      uint2 r[8];
#pragma unroll
      for (int j = 0; j < 8; j++) r[j] = *(const uint2*)&xh[(size_t)s[j] * DFEAT + c4];
#pragma unroll
      for (int j = 0; j < 8; j++) {
        float wa = fmaxf(w[j], 0.f);       // conv edges: +w
        float wb = fmaxf(-w[j], 0.f);      // ctrl edges: -w
        float e0 = __uint_as_float(r[j].x << 16);
        float e1 = __uint_as_float(r[j].x & 0xffff0000u);
        float e2 = __uint_as_float(r[j].y << 16);
        float e3 = __uint_as_float(r[j].y & 0xffff0000u);
        a0 = fmaf(wa, e0, a0); a1 = fmaf(wa, e1, a1);
        a2 = fmaf(wa, e2, a2); a3 = fmaf(wa, e3, a3);
        b0 = fmaf(wb, e0, b0); b1 = fmaf(wb, e1, b1);
        b2 = fmaf(wb, e2, b2); b3 = fmaf(wb, e3, b3);
      }
    }
  }

  u32x2 oa, ob;
  oa.x = (uint)f2bf(dc * a0) | ((uint)f2bf(dc * a1) << 16);
  oa.y = (uint)f2bf(dc * a2) | ((uint)f2bf(dc * a3) << 16);
  ob.x = (uint)f2bf(dt * b0) | ((uint)f2bf(dt * b1) << 16);
  ob.y = (uint)f2bf(dt * b2) | ((uint)f2bf(dt * b3) << 16);
  __builtin_nontemporal_store(oa, (u32x2*)&aggc[(size_t)node * DFEAT + c4]);
  __builtin_nontemporal_store(ob, (u32x2*)&aggt[(size_t)node * DFEAT + c4]);
}

// ---------- fused K=256 GEMM (R3 best-measured): prefetch + 2-tile LDS, NT A-loads ----------
// Operand-swapped mfma -> packed ushort4/float4 row-major stores.
__global__ __launch_bounds__(256, 2) void gemmf_k(
    const ushort* __restrict__ ac, const ushort* __restrict__ at,
    const ushort* __restrict__ wTc, const ushort* __restrict__ wTt,
    const float* __restrict__ bc, const float* __restrict__ bt,
    float* __restrict__ outf, ushort* __restrict__ outh, int n, int last) {
  __shared__ __align__(16) ushort Bs[2][DFEAT * BPAD];
  __shared__ float bias[DFEAT];
  int tid = threadIdx.x;

#pragma unroll
  for (int it = 0; it < 8; it++) {
    int idx = tid + it * NT;          // 0..2047: 128 rows x 16 uint4
    int c = idx >> 4, i = idx & 15;
    *(uint4*)&Bs[0][c * BPAD + i * 8] = *(const uint4*)&wTc[c * DFEAT + i * 8];
    *(uint4*)&Bs[1][c * BPAD + i * 8] = *(const uint4*)&wTt[c * DFEAT + i * 8];
  }
  if (tid < DFEAT) bias[tid] = bc[tid] + bt[tid];
  __syncthreads();

  int wave = tid >> 6;
  int lane = tid & 63;
  int m = lane & 15;
  int q = lane >> 4;
  int row0 = blockIdx.x * GEMM_ROWS + wave * 32;
  int rA = min(row0 + m, n - 1);
  int rB = min(row0 + 16 + m, n - 1);

  u32x4 fA[8], fB[8];
#pragma unroll
  for (int ks = 0; ks < 8; ks++) {                 // K=256: 0..3 conv-half, 4..7 ctrl-half
    const ushort* A = (ks < 4) ? ac : at;
    int ko = (ks & 3) * 32 + q * 8;
    fA[ks] = __builtin_nontemporal_load((const u32x4*)&A[(size_t)rA * DFEAT + ko]);
    fB[ks] = __builtin_nontemporal_load((const u32x4*)&A[(size_t)rB * DFEAT + ko]);
  }

  f32x4 zero4 = {0.f, 0.f, 0.f, 0.f};
  f32x4 acc0[8], acc1[8];
#pragma unroll
  for (int i = 0; i < 8; i++) { acc0[i] = zero4; acc1[i] = zero4; }

#pragma unroll
  for (int ks = 0; ks < 8; ks++) {
    int ko = (ks & 3) * 32 + q * 8;
    union { u32x4 u; s8v s; } uA, uB; uA.u = fA[ks]; uB.u = fB[ks];
#pragma unroll
    for (int c8 = 0; c8 < 8; c8++) {
      s8v bf = *(const s8v*)&Bs[ks >> 2][(c8 * 16 + m) * BPAD + ko];
      acc0[c8] = __builtin_amdgcn_mfma_f32_16x16x32_bf16(bf, uA.s, acc0[c8], 0, 0, 0);
      acc1[c8] = __builtin_amdgcn_mfma_f32_16x16x32_bf16(bf, uB.s, acc1[c8], 0, 0, 0);
    }
  }

#pragma unroll
  for (int sub = 0; sub < 2; sub++) {
    int orow = row0 + sub * 16 + m;
    if (orow < n) {
#pragma unroll
      for (int c8 = 0; c8 < 8; c8++) {
        f32x4 a = sub ? acc1[c8] : acc0[c8];
        int col = c8 * 16 + q * 4;
        float4 bv = *(const float4*)&bias[col];
        float o0 = a[0] + bv.x, o1 = a[1] + bv.y, o2 = a[2] + bv.z, o3 = a[3] + bv.w;
        if (last) {
          *(float4*)&outf[(size_t)orow * DFEAT + col] = make_float4(o0, o1, o2, o3);
        } else {
          ushort4 h;
          h.x = f2bf(fmaxf(o0, 0.f));
          h.y = f2bf(fmaxf(o1, 0.f));
          h.z = f2bf(fmaxf(o2, 0.f));
          h.w = f2bf(fmaxf(o3, 0.f));
          *(ushort4*)&outh[(size_t)orow * DFEAT + col] = h;
        }
      }
    }
  }
}

extern "C" void kernel_launch(void* const* d_in, const int* in_sizes, int n_in,
                              void* d_out, int out_size, void* d_ws, size_t ws_size,
                              hipStream_t stream) {
  const float* x0 = (const float*)d_in[0];
  const int*   ei = (const int*)d_in[1];
  const int*   ci = (const int*)d_in[2];
  const float* Wc = (const float*)d_in[3];
  const float* bc = (const float*)d_in[4];
  const float* Wt = (const float*)d_in[5];
  const float* bt = (const float*)d_in[6];
  float* out = (float*)d_out;

  int n  = in_sizes[0] / DFEAT;     // 100000
  int E  = in_sizes[1] / 2;         // 600000
  int EC = in_sizes[2] / 2;         // 200000
  int etot = E + EC;

  const int* e_src = ei;
  const int* e_dst = ei + E;
  const int* c_src = ci;
  const int* c_dst = ci + EC;

  char* p = (char*)d_ws;
  ushort* agg_c = (ushort*)p; p += (size_t)n * DFEAT * 2;
  ushort* agg_t = (ushort*)p; p += (size_t)n * DFEAT * 2;
  ushort* xh  = (ushort*)p; p += (size_t)n * DFEAT * 2;
  ushort* wT  = (ushort*)p; p += (size_t)8 * DFEAT * DFEAT * 2;
  float* dall = (float*)p; p += (size_t)2 * n * 4;
  int* cnt_c = (int*)p; p += (size_t)n * 4;     // histogram -> cursor
  int* cnt_t = (int*)p; p += (size_t)n * 4;
  int* rp    = (int*)p; p += (size_t)(n + 1) * 4;
  int* csr   = (int*)p; p += (size_t)etot * 4;
  float* wv  = (float*)p; p += (size_t)etot * 4;
  int* bsum  = (int*)p;

  int nb_scan  = (n + SCAN_ELEMS - 1) / SCAN_ELEMS;
  int nb_gemm  = (n + GEMM_ROWS - 1) / GEMM_ROWS;
  int nb_node  = (n + 7) / 8;
  int nbh = (etot + NT - 1) / NT;               // hist section blocks
  int nbx = (n * 32 + NT - 1) / NT;             // convx section blocks
  int nbw = (8 * DFEAT * DFEAT) / NT;           // convw section blocks

  // ---- build merged CSR + dinv + weights; conversions overlapped in megapre ----
  (void)hipMemsetAsync(cnt_c, 0, (size_t)2 * n * 4, stream);
  megapre_k<<<nbh + nbx + nbw, NT, 0, stream>>>(e_dst, E, c_dst, EC, cnt_c, cnt_t,
                                                x0, xh, n * 32, Wc, Wt, wT, nbh, nbx);
  scan_partial_md<<<nb_scan, NT, 0, stream>>>(cnt_c, cnt_t, n, bsum, dall);
  scan_offsets_m<<<1, NT, 0, stream>>>(bsum, nb_scan, rp, n);
  scan_final_m<<<nb_scan, NT, 0, stream>>>(cnt_c, cnt_t, n, bsum, rp);
  fill_k<<<(etot + NT - 1) / NT, NT, 0, stream>>>(e_src, e_dst, E, c_src, c_dst, EC,
                                                  cnt_c, csr);
  wv_k<<<(etot + NT - 1) / NT, NT, 0, stream>>>(csr, dall, wv, etot, n);

  // ---- layers: merged-CSR aggregate (chunk-8, NT stores) + fused K=256 GEMM ----
  for (int i = 0; i < 4; i++) {
    aggregate8_k<<<nb_node, NT, 0, stream>>>(xh, rp, csr, wv, dall, agg_c, agg_t, n);
    gemmf_k<<<nb_gemm, NT, 0, stream>>>(agg_c, agg_t,
                                        wT + (size_t)i * DFEAT * DFEAT,
                                        wT + (size_t)(4 + i) * DFEAT * DFEAT,
                                        bc + i * DFEAT, bt + i * DFEAT,
                                        out, xh, n, (i == 3) ? 1 : 0);
  }
}

// Round 11
// 447.374 us; speedup vs baseline: 1.5088x; 1.0271x over previous
//
#include <hip/hip_runtime.h>
#include <cstdint>
#include <cstddef>

#define NT 256
#define DFEAT 128
#define SCAN_ELEMS 1024
#define GEMM_ROWS 128    // rows per gemm block (4 waves x 32 rows)
#define BPAD 136         // padded LDS k-stride (ushorts) for W^T tiles
#define CTRL_FLAG 0x40000000
#define SRC_MASK  0x3fffffff
#define FCE 2048         // edges per fillx chunk

typedef __attribute__((ext_vector_type(8))) short s8v;
typedef __attribute__((ext_vector_type(4))) float f32x4;
typedef __attribute__((ext_vector_type(2))) uint u32x2;   // nontemporal-compatible
typedef __attribute__((ext_vector_type(4))) uint u32x4;   // nontemporal-compatible

__device__ inline ushort f2bf(float f) {           // RNE fp32 -> bf16
  uint32_t u = __float_as_uint(f);
  u += 0x7fffu + ((u >> 16) & 1u);
  return (ushort)(u >> 16);
}

// ---------- megapre: hist (atomics) + convx (stream) + convw, one dispatch ----------
__global__ void megapre_k(const int* __restrict__ e_dst, int E,
                          const int* __restrict__ c_dst, int EC,
                          int* __restrict__ cnt_c, int* __restrict__ cnt_t,
                          const float* __restrict__ x, ushort* __restrict__ xh, int total4,
                          const float* __restrict__ Wc, const float* __restrict__ Wt,
                          ushort* __restrict__ wT, int nbh, int nbx) {
  int b = blockIdx.x;
  if (b < nbh) {                       // ---- histogram section ----
    int i = b * NT + threadIdx.x;
    if (i < E) atomicAdd(&cnt_c[e_dst[i]], 1);
    else if (i < E + EC) atomicAdd(&cnt_t[c_dst[i - E]], 1);
  } else if (b < nbh + nbx) {          // ---- convx section ----
    int i = (b - nbh) * NT + threadIdx.x;
    if (i < total4) {
      float4 v = ((const float4*)x)[i];
      ushort4 o;
      o.x = f2bf(v.x); o.y = f2bf(v.y); o.z = f2bf(v.z); o.w = f2bf(v.w);
      ((ushort4*)xh)[i] = o;
    }
  } else {                             // ---- convw section ----
    int gid = (b - nbh - nbx) * NT + threadIdx.x;   // 0 .. 8*128*128
    int l = gid >> 14, rem = gid & 16383;
    int c = rem >> 7, k = rem & 127;
    const float* W = (l < 4) ? (Wc + (size_t)l * 16384) : (Wt + (size_t)(l - 4) * 16384);
    wT[gid] = f2bf(W[k * DFEAT + c]);
  }
}

// ---------- merged scan pass A + fused dinv (dall[0..n)=conv, [n..2n)=ctrl) ----------
__global__ __launch_bounds__(NT) void scan_partial_md(
    const int* __restrict__ cnt_c, const int* __restrict__ cnt_t, int n,
    int* __restrict__ bsum, float* __restrict__ dall) {
  int base = blockIdx.x * SCAN_ELEMS + threadIdx.x * 4;
  int s = 0;
  if (base + 3 < n) {
    int4 a = *(const int4*)&cnt_c[base];
    int4 b = *(const int4*)&cnt_t[base];
    s = a.x + a.y + a.z + a.w + b.x + b.y + b.z + b.w;
    float4 da, db;
    da.x = rsqrtf((float)(a.x + 1)); da.y = rsqrtf((float)(a.y + 1));
    da.z = rsqrtf((float)(a.z + 1)); da.w = rsqrtf((float)(a.w + 1));
    db.x = rsqrtf((float)(b.x + 1)); db.y = rsqrtf((float)(b.y + 1));
    db.z = rsqrtf((float)(b.z + 1)); db.w = rsqrtf((float)(b.w + 1));
    *(float4*)&dall[base] = da;
    *(float4*)&dall[n + base] = db;
  } else {
    for (int j = 0; j < 4; j++)
      if (base + j < n) {
        int a = cnt_c[base + j], b = cnt_t[base + j];
        s += a + b;
        dall[base + j] = rsqrtf((float)(a + 1));
        dall[n + base + j] = rsqrtf((float)(b + 1));
      }
  }
  for (int off = 32; off > 0; off >>= 1) s += __shfl_down(s, off, 64);
  __shared__ int ws[4];
  int lane = threadIdx.x & 63, w = threadIdx.x >> 6;
  if (lane == 0) ws[w] = s;
  __syncthreads();
  if (threadIdx.x == 0) bsum[blockIdx.x] = ws[0] + ws[1] + ws[2] + ws[3];
}

// ---------- merged scan pass B ----------
__global__ __launch_bounds__(NT) void scan_offsets_m(
    int* __restrict__ bsum, int nb, int* __restrict__ rp, int n) {
  __shared__ int ls[NT];
  int t = threadIdx.x;
  int v = (t < nb) ? bsum[t] : 0;
  ls[t] = v;
  __syncthreads();
  for (int off = 1; off < NT; off <<= 1) {
    int u = (t >= off) ? ls[t - off] : 0;
    __syncthreads();
    ls[t] += u;
    __syncthreads();
  }
  if (t < nb) bsum[t] = ls[t] - v;
  if (t == nb - 1) rp[n] = ls[t];
}

// ---------- merged scan pass C: rowptr + absolute cursor in cnt_c ----------
__global__ __launch_bounds__(NT) void scan_final_m(
    int* __restrict__ cnt_c, const int* __restrict__ cnt_t, int n,
    const int* __restrict__ bsum, int* __restrict__ rp) {
  int offset = bsum[blockIdx.x];
  int base = blockIdx.x * SCAN_ELEMS + threadIdx.x * 4;

  int4 v = make_int4(0, 0, 0, 0);
  if (base + 3 < n) {
    int4 a = *(const int4*)&cnt_c[base];
    int4 b = *(const int4*)&cnt_t[base];
    v = make_int4(a.x + b.x, a.y + b.y, a.z + b.z, a.w + b.w);
  } else {
    if (base + 0 < n) v.x = cnt_c[base + 0] + cnt_t[base + 0];
    if (base + 1 < n) v.y = cnt_c[base + 1] + cnt_t[base + 1];
    if (base + 2 < n) v.z = cnt_c[base + 2] + cnt_t[base + 2];
    if (base + 3 < n) v.w = cnt_c[base + 3] + cnt_t[base + 3];
  }
  int tsum = v.x + v.y + v.z + v.w;

  __shared__ int ls[NT];
  int t = threadIdx.x;
  ls[t] = tsum;
  __syncthreads();
  for (int off = 1; off < NT; off <<= 1) {
    int u = (t >= off) ? ls[t - off] : 0;
    __syncthreads();
    ls[t] += u;
    __syncthreads();
  }
  int excl = offset + ls[t] - tsum;

  int4 o;
  o.x = excl;
  o.y = o.x + v.x;
  o.z = o.y + v.y;
  o.w = o.z + v.z;
  if (base + 3 < n) {
    *(int4*)&rp[base] = o;
    *(int4*)&cnt_c[base] = o;   // cursor = absolute row start
  } else {
    if (base + 0 < n) { rp[base + 0] = o.x; cnt_c[base + 0] = o.x; }
    if (base + 1 < n) { rp[base + 1] = o.y; cnt_c[base + 1] = o.y; }
    if (base + 2 < n) { rp[base + 2] = o.z; cnt_c[base + 2] = o.z; }
    if (base + 3 < n) { rp[base + 3] = o.w; cnt_c[base + 3] = o.w; }
  }
}

// ---------- XCD-partitioned fill of the merged CSR ----------
// Block b -> edge chunk b/8, dst range b%8. Consecutive blockIdx round-robin across
// the 8 XCDs, so range r's csr/cursor lines are dirtied from exactly ONE per-XCD L2:
// each 64B line is fully assembled before write-back (fixes the 17x write-amp seen
// as WRITE_SIZE=55MB for a 3.2MB CSR). Edge re-reads (8x) are L3-served (6.4MB).
// If the mapping assumption fails, correctness is unaffected (just slower).
__global__ void fillx_k(const int* __restrict__ e_src, const int* __restrict__ e_dst, int E,
                        const int* __restrict__ c_src, const int* __restrict__ c_dst, int EC,
                        int* __restrict__ cur, int* __restrict__ csr, int n) {
  int slot = blockIdx.x & 7;
  int chunk = blockIdx.x >> 3;
  int lo = (int)(((long long)slot * n) >> 3);
  int hi = (int)(((long long)(slot + 1) * n) >> 3);
  int start = chunk * FCE;
  int end = min(start + FCE, E + EC);
  for (int i = start + (int)threadIdx.x; i < end; i += NT) {
    if (i < E) {
      int d = e_dst[i];
      if (d >= lo && d < hi) csr[atomicAdd(&cur[d], 1)] = e_src[i];
    } else {
      int j = i - E;
      int d = c_dst[j];
      if (d >= lo && d < hi) csr[atomicAdd(&cur[d], 1)] = c_src[j] | CTRL_FLAG;
    }
  }
}

// ---------- per-edge signed weight: wv[e] = (+/-) dinv[src] (ctrl = negative) ----------
__global__ void wv_k(const int* __restrict__ csr, const float* __restrict__ dall,
                     float* __restrict__ wv, int etot, int n) {
  int i = blockIdx.x * NT + threadIdx.x;
  if (i < etot) {
    int v = csr[i];
    int s = v & SRC_MASK;
    int f = (v >> 30) & 1;
    float w = dall[s + f * n];
    wv[i] = f ? -w : w;
  }
}

// ---------- merged-CSR aggregate: 1 node/group, chunk-8, signed wv, NT stores ----------
__global__ __launch_bounds__(256) void aggregate8_k(
    const ushort* __restrict__ xh,
    const int* __restrict__ rp, const int* __restrict__ cs, const float* __restrict__ wv,
    const float* __restrict__ dall,
    ushort* __restrict__ aggc, ushort* __restrict__ aggt, int n) {
  int node = blockIdx.x * 8 + (threadIdx.x >> 5);
  if (node >= n) return;
  int lane = threadIdx.x & 31;
  int c4 = lane << 2;

  float dc = dall[node], dt = dall[n + node];
  uint2 sv0 = *(const uint2*)&xh[(size_t)node * DFEAT + c4];
  float x0 = __uint_as_float(sv0.x << 16);
  float x1 = __uint_as_float(sv0.x & 0xffff0000u);
  float x2 = __uint_as_float(sv0.y << 16);
  float x3 = __uint_as_float(sv0.y & 0xffff0000u);

  float a0 = dc * x0, a1 = dc * x1, a2 = dc * x2, a3 = dc * x3;   // conv acc
  float b0 = dt * x0, b1 = dt * x1, b2 = dt * x2, b3 = dt * x3;   // ctrl acc

  int s0 = rp[node], deg = rp[node + 1] - s0;
  for (int p = 0; p < deg; p += 32) {
    int rem = deg - p;                     // > 0
    int mm = min(32, rem);
    int idx = s0 + p + min(lane, rem - 1); // clamped: always valid edge slot
    int sv = cs[idx] & SRC_MASK;
    float wl = wv[idx];                    // parallel with cs load
    float ws = (lane < mm) ? wl : 0.f;
    for (int k = 0; k < mm; k += 8) {
      int s[8]; float w[8];
#pragma unroll
      for (int j = 0; j < 8; j++) {
        s[j] = __shfl(sv, k + j, 32);
        w[j] = __shfl(ws, k + j, 32);
      }
      uint2 r[8];
#pragma unroll
      for (int j = 0; j < 8; j++) r[j] = *(const uint2*)&xh[(size_t)s[j] * DFEAT + c4];
#pragma unroll
      for (int j = 0; j < 8; j++) {
        float wa = fmaxf(w[j], 0.f);       // conv edges: +w
        float wb = fmaxf(-w[j], 0.f);      // ctrl edges: -w
        float e0 = __uint_as_float(r[j].x << 16);
        float e1 = __uint_as_float(r[j].x & 0xffff0000u);
        float e2 = __uint_as_float(r[j].y << 16);
        float e3 = __uint_as_float(r[j].y & 0xffff0000u);
        a0 = fmaf(wa, e0, a0); a1 = fmaf(wa, e1, a1);
        a2 = fmaf(wa, e2, a2); a3 = fmaf(wa, e3, a3);
        b0 = fmaf(wb, e0, b0); b1 = fmaf(wb, e1, b1);
        b2 = fmaf(wb, e2, b2); b3 = fmaf(wb, e3, b3);
      }
    }
  }

  u32x2 oa, ob;
  oa.x = (uint)f2bf(dc * a0) | ((uint)f2bf(dc * a1) << 16);
  oa.y = (uint)f2bf(dc * a2) | ((uint)f2bf(dc * a3) << 16);
  ob.x = (uint)f2bf(dt * b0) | ((uint)f2bf(dt * b1) << 16);
  ob.y = (uint)f2bf(dt * b2) | ((uint)f2bf(dt * b3) << 16);
  __builtin_nontemporal_store(oa, (u32x2*)&aggc[(size_t)node * DFEAT + c4]);
  __builtin_nontemporal_store(ob, (u32x2*)&aggt[(size_t)node * DFEAT + c4]);
}

// ---------- fused K=256 GEMM: prefetch + 2-tile LDS, NT A-loads ----------
// Operand-swapped mfma -> packed ushort4/float4 row-major stores.
__global__ __launch_bounds__(256, 2) void gemmf_k(
    const ushort* __restrict__ ac, const ushort* __restrict__ at,
    const ushort* __restrict__ wTc, const ushort* __restrict__ wTt,
    const float* __restrict__ bc, const float* __restrict__ bt,
    float* __restrict__ outf, ushort* __restrict__ outh, int n, int last) {
  __shared__ __align__(16) ushort Bs[2][DFEAT * BPAD];
  __shared__ float bias[DFEAT];
  int tid = threadIdx.x;

#pragma unroll
  for (int it = 0; it < 8; it++) {
    int idx = tid + it * NT;          // 0..2047: 128 rows x 16 uint4
    int c = idx >> 4, i = idx & 15;
    *(uint4*)&Bs[0][c * BPAD + i * 8] = *(const uint4*)&wTc[c * DFEAT + i * 8];
    *(uint4*)&Bs[1][c * BPAD + i * 8] = *(const uint4*)&wTt[c * DFEAT + i * 8];
  }
  if (tid < DFEAT) bias[tid] = bc[tid] + bt[tid];
  __syncthreads();

  int wave = tid >> 6;
  int lane = tid & 63;
  int m = lane & 15;
  int q = lane >> 4;
  int row0 = blockIdx.x * GEMM_ROWS + wave * 32;
  int rA = min(row0 + m, n - 1);
  int rB = min(row0 + 16 + m, n - 1);

  u32x4 fA[8], fB[8];
#pragma unroll
  for (int ks = 0; ks < 8; ks++) {                 // K=256: 0..3 conv-half, 4..7 ctrl-half
    const ushort* A = (ks < 4) ? ac : at;
    int ko = (ks & 3) * 32 + q * 8;
    fA[ks] = __builtin_nontemporal_load((const u32x4*)&A[(size_t)rA * DFEAT + ko]);
    fB[ks] = __builtin_nontemporal_load((const u32x4*)&A[(size_t)rB * DFEAT + ko]);
  }

  f32x4 zero4 = {0.f, 0.f, 0.f, 0.f};
  f32x4 acc0[8], acc1[8];
#pragma unroll
  for (int i = 0; i < 8; i++) { acc0[i] = zero4; acc1[i] = zero4; }

#pragma unroll
  for (int ks = 0; ks < 8; ks++) {
    int ko = (ks & 3) * 32 + q * 8;
    union { u32x4 u; s8v s; } uA, uB; uA.u = fA[ks]; uB.u = fB[ks];
#pragma unroll
    for (int c8 = 0; c8 < 8; c8++) {
      s8v bf = *(const s8v*)&Bs[ks >> 2][(c8 * 16 + m) * BPAD + ko];
      acc0[c8] = __builtin_amdgcn_mfma_f32_16x16x32_bf16(bf, uA.s, acc0[c8], 0, 0, 0);
      acc1[c8] = __builtin_amdgcn_mfma_f32_16x16x32_bf16(bf, uB.s, acc1[c8], 0, 0, 0);
    }
  }

#pragma unroll
  for (int sub = 0; sub < 2; sub++) {
    int orow = row0 + sub * 16 + m;
    if (orow < n) {
#pragma unroll
      for (int c8 = 0; c8 < 8; c8++) {
        f32x4 a = sub ? acc1[c8] : acc0[c8];
        int col = c8 * 16 + q * 4;
        float4 bv = *(const float4*)&bias[col];
        float o0 = a[0] + bv.x, o1 = a[1] + bv.y, o2 = a[2] + bv.z, o3 = a[3] + bv.w;
        if (last) {
          *(float4*)&outf[(size_t)orow * DFEAT + col] = make_float4(o0, o1, o2, o3);
        } else {
          ushort4 h;
          h.x = f2bf(fmaxf(o0, 0.f));
          h.y = f2bf(fmaxf(o1, 0.f));
          h.z = f2bf(fmaxf(o2, 0.f));
          h.w = f2bf(fmaxf(o3, 0.f));
          *(ushort4*)&outh[(size_t)orow * DFEAT + col] = h;
        }
      }
    }
  }
}

extern "C" void kernel_launch(void* const* d_in, const int* in_sizes, int n_in,
                              void* d_out, int out_size, void* d_ws, size_t ws_size,
                              hipStream_t stream) {
  const float* x0 = (const float*)d_in[0];
  const int*   ei = (const int*)d_in[1];
  const int*   ci = (const int*)d_in[2];
  const float* Wc = (const float*)d_in[3];
  const float* bc = (const float*)d_in[4];
  const float* Wt = (const float*)d_in[5];
  const float* bt = (const float*)d_in[6];
  float* out = (float*)d_out;

  int n  = in_sizes[0] / DFEAT;     // 100000
  int E  = in_sizes[1] / 2;         // 600000
  int EC = in_sizes[2] / 2;         // 200000
  int etot = E + EC;

  const int* e_src = ei;
  const int* e_dst = ei + E;
  const int* c_src = ci;
  const int* c_dst = ci + EC;

  char* p = (char*)d_ws;
  ushort* agg_c = (ushort*)p; p += (size_t)n * DFEAT * 2;
  ushort* agg_t = (ushort*)p; p += (size_t)n * DFEAT * 2;
  ushort* xh  = (ushort*)p; p += (size_t)n * DFEAT * 2;
  ushort* wT  = (ushort*)p; p += (size_t)8 * DFEAT * DFEAT * 2;
  float* dall = (float*)p; p += (size_t)2 * n * 4;
  int* cnt_c = (int*)p; p += (size_t)n * 4;     // histogram -> cursor
  int* cnt_t = (int*)p; p += (size_t)n * 4;
  int* rp    = (int*)p; p += (size_t)(n + 1) * 4;
  int* csr   = (int*)p; p += (size_t)etot * 4;
  float* wv  = (float*)p; p += (size_t)etot * 4;
  int* bsum  = (int*)p;

  int nb_scan  = (n + SCAN_ELEMS - 1) / SCAN_ELEMS;
  int nb_gemm  = (n + GEMM_ROWS - 1) / GEMM_ROWS;
  int nb_node  = (n + 7) / 8;
  int nbh = (etot + NT - 1) / NT;               // hist section blocks
  int nbx = (n * 32 + NT - 1) / NT;             // convx section blocks
  int nbw = (8 * DFEAT * DFEAT) / NT;           // convw section blocks
  int nb_fillx = ((etot + FCE - 1) / FCE) * 8;

  // ---- build merged CSR + dinv + weights; conversions overlapped in megapre ----
  (void)hipMemsetAsync(cnt_c, 0, (size_t)2 * n * 4, stream);
  megapre_k<<<nbh + nbx + nbw, NT, 0, stream>>>(e_dst, E, c_dst, EC, cnt_c, cnt_t,
                                                x0, xh, n * 32, Wc, Wt, wT, nbh, nbx);
  scan_partial_md<<<nb_scan, NT, 0, stream>>>(cnt_c, cnt_t, n, bsum, dall);
  scan_offsets_m<<<1, NT, 0, stream>>>(bsum, nb_scan, rp, n);
  scan_final_m<<<nb_scan, NT, 0, stream>>>(cnt_c, cnt_t, n, bsum, rp);
  fillx_k<<<nb_fillx, NT, 0, stream>>>(e_src, e_dst, E, c_src, c_dst, EC,
                                       cnt_c, csr, n);
  wv_k<<<(etot + NT - 1) / NT, NT, 0, stream>>>(csr, dall, wv, etot, n);

  // ---- layers: merged-CSR aggregate (chunk-8, NT stores) + fused K=256 GEMM ----
  for (int i = 0; i < 4; i++) {
    aggregate8_k<<<nb_node, NT, 0, stream>>>(xh, rp, csr, wv, dall, agg_c, agg_t, n);
    gemmf_k<<<nb_gemm, NT, 0, stream>>>(agg_c, agg_t,
                                        wT + (size_t)i * DFEAT * DFEAT,
                                        wT + (size_t)(4 + i) * DFEAT * DFEAT,
                                        bc + i * DFEAT, bt + i * DFEAT,
                                        out, xh, n, (i == 3) ? 1 : 0);
  }
}

// Round 12
// 442.924 us; speedup vs baseline: 1.5239x; 1.0100x over previous
//
#include <hip/hip_runtime.h>
#include <cstdint>
#include <cstddef>

#define NT 256
#define DFEAT 128
#define SCAN_ELEMS 1024
#define GEMM_ROWS 128    // rows per gemm block (4 waves x 32 rows)
#define BPAD 136         // padded LDS k-stride (ushorts) for W^T tiles
#define FCE 2048         // edges per XCD-partitioned chunk (hist + fill)

typedef __attribute__((ext_vector_type(8))) short s8v;
typedef __attribute__((ext_vector_type(4))) float f32x4;
typedef __attribute__((ext_vector_type(2))) uint u32x2;   // nontemporal-compatible
typedef __attribute__((ext_vector_type(4))) uint u32x4;   // nontemporal-compatible

__device__ inline ushort f2bf(float f) {           // RNE fp32 -> bf16
  uint32_t u = __float_as_uint(f);
  u += 0x7fffu + ((u >> 16) & 1u);
  return (ushort)(u >> 16);
}

// ---------- megapre: XCD-partitioned hist + convx (stream) + convw, one dispatch ----------
// Hist section uses the fillx pattern: block b -> edge chunk b/8, dst range b%8.
// All atomics on a given cnt line come from ONE XCD's L2 -> line assembled locally,
// written back once (fixes the ~25MB atomic write-amp seen in R11's WRITE_SIZE).
__global__ void megapre_k(const int* __restrict__ e_dst, int E,
                          const int* __restrict__ c_dst, int EC,
                          int* __restrict__ cnt_c, int* __restrict__ cnt_t,
                          const float* __restrict__ x, ushort* __restrict__ xh, int total4,
                          const float* __restrict__ Wc, const float* __restrict__ Wt,
                          ushort* __restrict__ wT, int nbhx, int nbx, int n) {
  int b = blockIdx.x;
  if (b < nbhx) {                      // ---- XCD-partitioned histogram section ----
    int slot = b & 7;
    int chunk = b >> 3;
    int lo = (int)(((long long)slot * n) >> 3);
    int hi = (int)(((long long)(slot + 1) * n) >> 3);
    int start = chunk * FCE;
    int end = min(start + FCE, E + EC);
    for (int i = start + (int)threadIdx.x; i < end; i += NT) {
      if (i < E) {
        int d = e_dst[i];
        if (d >= lo && d < hi) atomicAdd(&cnt_c[d], 1);
      } else {
        int d = c_dst[i - E];
        if (d >= lo && d < hi) atomicAdd(&cnt_t[d], 1);
      }
    }
  } else if (b < nbhx + nbx) {         // ---- convx section ----
    int i = (b - nbhx) * NT + threadIdx.x;
    if (i < total4) {
      float4 v = ((const float4*)x)[i];
      ushort4 o;
      o.x = f2bf(v.x); o.y = f2bf(v.y); o.z = f2bf(v.z); o.w = f2bf(v.w);
      ((ushort4*)xh)[i] = o;
    }
  } else {                             // ---- convw section ----
    int gid = (b - nbhx - nbx) * NT + threadIdx.x;   // 0 .. 8*128*128
    int l = gid >> 14, rem = gid & 16383;
    int c = rem >> 7, k = rem & 127;
    const float* W = (l < 4) ? (Wc + (size_t)l * 16384) : (Wt + (size_t)(l - 4) * 16384);
    wT[gid] = f2bf(W[k * DFEAT + c]);
  }
}

// ---------- merged scan pass A + fused dinv (dall[0..n)=conv, [n..2n)=ctrl) ----------
__global__ __launch_bounds__(NT) void scan_partial_md(
    const int* __restrict__ cnt_c, const int* __restrict__ cnt_t, int n,
    int* __restrict__ bsum, float* __restrict__ dall) {
  int base = blockIdx.x * SCAN_ELEMS + threadIdx.x * 4;
  int s = 0;
  if (base + 3 < n) {
    int4 a = *(const int4*)&cnt_c[base];
    int4 b = *(const int4*)&cnt_t[base];
    s = a.x + a.y + a.z + a.w + b.x + b.y + b.z + b.w;
    float4 da, db;
    da.x = rsqrtf((float)(a.x + 1)); da.y = rsqrtf((float)(a.y + 1));
    da.z = rsqrtf((float)(a.z + 1)); da.w = rsqrtf((float)(a.w + 1));
    db.x = rsqrtf((float)(b.x + 1)); db.y = rsqrtf((float)(b.y + 1));
    db.z = rsqrtf((float)(b.z + 1)); db.w = rsqrtf((float)(b.w + 1));
    *(float4*)&dall[base] = da;
    *(float4*)&dall[n + base] = db;
  } else {
    for (int j = 0; j < 4; j++)
      if (base + j < n) {
        int a = cnt_c[base + j], b = cnt_t[base + j];
        s += a + b;
        dall[base + j] = rsqrtf((float)(a + 1));
        dall[n + base + j] = rsqrtf((float)(b + 1));
      }
  }
  for (int off = 32; off > 0; off >>= 1) s += __shfl_down(s, off, 64);
  __shared__ int ws[4];
  int lane = threadIdx.x & 63, w = threadIdx.x >> 6;
  if (lane == 0) ws[w] = s;
  __syncthreads();
  if (threadIdx.x == 0) bsum[blockIdx.x] = ws[0] + ws[1] + ws[2] + ws[3];
}

// ---------- merged scan pass B ----------
__global__ __launch_bounds__(NT) void scan_offsets_m(
    int* __restrict__ bsum, int nb, int* __restrict__ rp, int n) {
  __shared__ int ls[NT];
  int t = threadIdx.x;
  int v = (t < nb) ? bsum[t] : 0;
  ls[t] = v;
  __syncthreads();
  for (int off = 1; off < NT; off <<= 1) {
    int u = (t >= off) ? ls[t - off] : 0;
    __syncthreads();
    ls[t] += u;
    __syncthreads();
  }
  if (t < nb) bsum[t] = ls[t] - v;
  if (t == nb - 1) rp[n] = ls[t];
}

// ---------- merged scan pass C: rowptr + absolute cursor in cnt_c ----------
__global__ __launch_bounds__(NT) void scan_final_m(
    int* __restrict__ cnt_c, const int* __restrict__ cnt_t, int n,
    const int* __restrict__ bsum, int* __restrict__ rp) {
  int offset = bsum[blockIdx.x];
  int base = blockIdx.x * SCAN_ELEMS + threadIdx.x * 4;

  int4 v = make_int4(0, 0, 0, 0);
  if (base + 3 < n) {
    int4 a = *(const int4*)&cnt_c[base];
    int4 b = *(const int4*)&cnt_t[base];
    v = make_int4(a.x + b.x, a.y + b.y, a.z + b.z, a.w + b.w);
  } else {
    if (base + 0 < n) v.x = cnt_c[base + 0] + cnt_t[base + 0];
    if (base + 1 < n) v.y = cnt_c[base + 1] + cnt_t[base + 1];
    if (base + 2 < n) v.z = cnt_c[base + 2] + cnt_t[base + 2];
    if (base + 3 < n) v.w = cnt_c[base + 3] + cnt_t[base + 3];
  }
  int tsum = v.x + v.y + v.z + v.w;

  __shared__ int ls[NT];
  int t = threadIdx.x;
  ls[t] = tsum;
  __syncthreads();
  for (int off = 1; off < NT; off <<= 1) {
    int u = (t >= off) ? ls[t - off] : 0;
    __syncthreads();
    ls[t] += u;
    __syncthreads();
  }
  int excl = offset + ls[t] - tsum;

  int4 o;
  o.x = excl;
  o.y = o.x + v.x;
  o.z = o.y + v.y;
  o.w = o.z + v.z;
  if (base + 3 < n) {
    *(int4*)&rp[base] = o;
    *(int4*)&cnt_c[base] = o;   // cursor = absolute row start
  } else {
    if (base + 0 < n) { rp[base + 0] = o.x; cnt_c[base + 0] = o.x; }
    if (base + 1 < n) { rp[base + 1] = o.y; cnt_c[base + 1] = o.y; }
    if (base + 2 < n) { rp[base + 2] = o.z; cnt_c[base + 2] = o.z; }
    if (base + 3 < n) { rp[base + 3] = o.w; cnt_c[base + 3] = o.w; }
  }
}

// ---------- XCD-partitioned fill of merged CSR with inline packed (src, weight) ----------
// Block b -> edge chunk b/8, dst range b%8 (proven in R11: write-amp fix).
// Writes ecw[pos] = {src, +/-dinv[src]} in one 8B store; wv_k dispatch eliminated.
__global__ void fillx_k(const int* __restrict__ e_src, const int* __restrict__ e_dst, int E,
                        const int* __restrict__ c_src, const int* __restrict__ c_dst, int EC,
                        const float* __restrict__ dall,
                        int* __restrict__ cur, int2* __restrict__ ecw, int n) {
  int slot = blockIdx.x & 7;
  int chunk = blockIdx.x >> 3;
  int lo = (int)(((long long)slot * n) >> 3);
  int hi = (int)(((long long)(slot + 1) * n) >> 3);
  int start = chunk * FCE;
  int end = min(start + FCE, E + EC);
  for (int i = start + (int)threadIdx.x; i < end; i += NT) {
    if (i < E) {
      int d = e_dst[i];
      if (d >= lo && d < hi) {
        int s = e_src[i];
        int pos = atomicAdd(&cur[d], 1);
        ecw[pos] = make_int2(s, __float_as_int(dall[s]));            // conv: +w
      }
    } else {
      int j = i - E;
      int d = c_dst[j];
      if (d >= lo && d < hi) {
        int s = c_src[j];
        int pos = atomicAdd(&cur[d], 1);
        ecw[pos] = make_int2(s, __float_as_int(-dall[(size_t)n + s])); // ctrl: -w
      }
    }
  }
}

// ---------- merged-CSR aggregate: 1 node/group, chunk-8, packed edge (src,weight) ----------
__global__ __launch_bounds__(256) void aggregate9_k(
    const ushort* __restrict__ xh,
    const int* __restrict__ rp, const int2* __restrict__ ecw,
    const float* __restrict__ dall,
    ushort* __restrict__ aggc, ushort* __restrict__ aggt, int n) {
  int node = blockIdx.x * 8 + (threadIdx.x >> 5);
  if (node >= n) return;
  int lane = threadIdx.x & 31;
  int c4 = lane << 2;

  float dc = dall[node], dt = dall[n + node];
  uint2 sv0 = *(const uint2*)&xh[(size_t)node * DFEAT + c4];
  float x0 = __uint_as_float(sv0.x << 16);
  float x1 = __uint_as_float(sv0.x & 0xffff0000u);
  float x2 = __uint_as_float(sv0.y << 16);
  float x3 = __uint_as_float(sv0.y & 0xffff0000u);

  float a0 = dc * x0, a1 = dc * x1, a2 = dc * x2, a3 = dc * x3;   // conv acc
  float b0 = dt * x0, b1 = dt * x1, b2 = dt * x2, b3 = dt * x3;   // ctrl acc

  int s0 = rp[node], deg = rp[node + 1] - s0;
  for (int p = 0; p < deg; p += 32) {
    int rem = deg - p;                     // > 0
    int mm = min(32, rem);
    int idx = s0 + p + min(lane, rem - 1); // clamped: always valid edge slot
    int2 ev = ecw[idx];                    // one 8B load: (src, signed weight)
    int sv = ev.x;
    float ws = (lane < mm) ? __int_as_float(ev.y) : 0.f;
    for (int k = 0; k < mm; k += 8) {
      int s[8]; float w[8];
#pragma unroll
      for (int j = 0; j < 8; j++) {
        s[j] = __shfl(sv, k + j, 32);
        w[j] = __shfl(ws, k + j, 32);
      }
      uint2 r[8];
#pragma unroll
      for (int j = 0; j < 8; j++) r[j] = *(const uint2*)&xh[(size_t)s[j] * DFEAT + c4];
#pragma unroll
      for (int j = 0; j < 8; j++) {
        float wa = fmaxf(w[j], 0.f);       // conv edges: +w
        float wb = fmaxf(-w[j], 0.f);      // ctrl edges: -w
        float e0 = __uint_as_float(r[j].x << 16);
        float e1 = __uint_as_float(r[j].x & 0xffff0000u);
        float e2 = __uint_as_float(r[j].y << 16);
        float e3 = __uint_as_float(r[j].y & 0xffff0000u);
        a0 = fmaf(wa, e0, a0); a1 = fmaf(wa, e1, a1);
        a2 = fmaf(wa, e2, a2); a3 = fmaf(wa, e3, a3);
        b0 = fmaf(wb, e0, b0); b1 = fmaf(wb, e1, b1);
        b2 = fmaf(wb, e2, b2); b3 = fmaf(wb, e3, b3);
      }
    }
  }

  u32x2 oa, ob;
  oa.x = (uint)f2bf(dc * a0) | ((uint)f2bf(dc * a1) << 16);
  oa.y = (uint)f2bf(dc * a2) | ((uint)f2bf(dc * a3) << 16);
  ob.x = (uint)f2bf(dt * b0) | ((uint)f2bf(dt * b1) << 16);
  ob.y = (uint)f2bf(dt * b2) | ((uint)f2bf(dt * b3) << 16);
  __builtin_nontemporal_store(oa, (u32x2*)&aggc[(size_t)node * DFEAT + c4]);
  __builtin_nontemporal_store(ob, (u32x2*)&aggt[(size_t)node * DFEAT + c4]);
}

// ---------- fused K=256 GEMM: prefetch + 2-tile LDS, NT A-loads ----------
// Operand-swapped mfma -> packed ushort4/float4 row-major stores.
__global__ __launch_bounds__(256, 2) void gemmf_k(
    const ushort* __restrict__ ac, const ushort* __restrict__ at,
    const ushort* __restrict__ wTc, const ushort* __restrict__ wTt,
    const float* __restrict__ bc, const float* __restrict__ bt,
    float* __restrict__ outf, ushort* __restrict__ outh, int n, int last) {
  __shared__ __align__(16) ushort Bs[2][DFEAT * BPAD];
  __shared__ float bias[DFEAT];
  int tid = threadIdx.x;

#pragma unroll
  for (int it = 0; it < 8; it++) {
    int idx = tid + it * NT;          // 0..2047: 128 rows x 16 uint4
    int c = idx >> 4, i = idx & 15;
    *(uint4*)&Bs[0][c * BPAD + i * 8] = *(const uint4*)&wTc[c * DFEAT + i * 8];
    *(uint4*)&Bs[1][c * BPAD + i * 8] = *(const uint4*)&wTt[c * DFEAT + i * 8];
  }
  if (tid < DFEAT) bias[tid] = bc[tid] + bt[tid];
  __syncthreads();

  int wave = tid >> 6;
  int lane = tid & 63;
  int m = lane & 15;
  int q = lane >> 4;
  int row0 = blockIdx.x * GEMM_ROWS + wave * 32;
  int rA = min(row0 + m, n - 1);
  int rB = min(row0 + 16 + m, n - 1);

  u32x4 fA[8], fB[8];
#pragma unroll
  for (int ks = 0; ks < 8; ks++) {                 // K=256: 0..3 conv-half, 4..7 ctrl-half
    const ushort* A = (ks < 4) ? ac : at;
    int ko = (ks & 3) * 32 + q * 8;
    fA[ks] = __builtin_nontemporal_load((const u32x4*)&A[(size_t)rA * DFEAT + ko]);
    fB[ks] = __builtin_nontemporal_load((const u32x4*)&A[(size_t)rB * DFEAT + ko]);
  }

  f32x4 zero4 = {0.f, 0.f, 0.f, 0.f};
  f32x4 acc0[8], acc1[8];
#pragma unroll
  for (int i = 0; i < 8; i++) { acc0[i] = zero4; acc1[i] = zero4; }

#pragma unroll
  for (int ks = 0; ks < 8; ks++) {
    int ko = (ks & 3) * 32 + q * 8;
    union { u32x4 u; s8v s; } uA, uB; uA.u = fA[ks]; uB.u = fB[ks];
#pragma unroll
    for (int c8 = 0; c8 < 8; c8++) {
      s8v bf = *(const s8v*)&Bs[ks >> 2][(c8 * 16 + m) * BPAD + ko];
      acc0[c8] = __builtin_amdgcn_mfma_f32_16x16x32_bf16(bf, uA.s, acc0[c8], 0, 0, 0);
      acc1[c8] = __builtin_amdgcn_mfma_f32_16x16x32_bf16(bf, uB.s, acc1[c8], 0, 0, 0);
    }
  }

#pragma unroll
  for (int sub = 0; sub < 2; sub++) {
    int orow = row0 + sub * 16 + m;
    if (orow < n) {
#pragma unroll
      for (int c8 = 0; c8 < 8; c8++) {
        f32x4 a = sub ? acc1[c8] : acc0[c8];
        int col = c8 * 16 + q * 4;
        float4 bv = *(const float4*)&bias[col];
        float o0 = a[0] + bv.x, o1 = a[1] + bv.y, o2 = a[2] + bv.z, o3 = a[3] + bv.w;
        if (last) {
          *(float4*)&outf[(size_t)orow * DFEAT + col] = make_float4(o0, o1, o2, o3);
        } else {
          ushort4 h;
          h.x = f2bf(fmaxf(o0, 0.f));
          h.y = f2bf(fmaxf(o1, 0.f));
          h.z = f2bf(fmaxf(o2, 0.f));
          h.w = f2bf(fmaxf(o3, 0.f));
          *(ushort4*)&outh[(size_t)orow * DFEAT + col] = h;
        }
      }
    }
  }
}

extern "C" void kernel_launch(void* const* d_in, const int* in_sizes, int n_in,
                              void* d_out, int out_size, void* d_ws, size_t ws_size,
                              hipStream_t stream) {
  const float* x0 = (const float*)d_in[0];
  const int*   ei = (const int*)d_in[1];
  const int*   ci = (const int*)d_in[2];
  const float* Wc = (const float*)d_in[3];
  const float* bc = (const float*)d_in[4];
  const float* Wt = (const float*)d_in[5];
  const float* bt = (const float*)d_in[6];
  float* out = (float*)d_out;

  int n  = in_sizes[0] / DFEAT;     // 100000
  int E  = in_sizes[1] / 2;         // 600000
  int EC = in_sizes[2] / 2;         // 200000
  int etot = E + EC;

  const int* e_src = ei;
  const int* e_dst = ei + E;
  const int* c_src = ci;
  const int* c_dst = ci + EC;

  char* p = (char*)d_ws;
  ushort* agg_c = (ushort*)p; p += (size_t)n * DFEAT * 2;
  ushort* agg_t = (ushort*)p; p += (size_t)n * DFEAT * 2;
  ushort* xh  = (ushort*)p; p += (size_t)n * DFEAT * 2;
  ushort* wT  = (ushort*)p; p += (size_t)8 * DFEAT * DFEAT * 2;
  float* dall = (float*)p; p += (size_t)2 * n * 4;
  int* cnt_c = (int*)p; p += (size_t)n * 4;     // histogram -> cursor
  int* cnt_t = (int*)p; p += (size_t)n * 4;
  int* rp    = (int*)p; p += (size_t)(n + 1) * 4;
  int2* ecw  = (int2*)p; p += (size_t)etot * 8; // packed (src, signed weight)
  int* bsum  = (int*)p;

  int nb_scan  = (n + SCAN_ELEMS - 1) / SCAN_ELEMS;
  int nb_gemm  = (n + GEMM_ROWS - 1) / GEMM_ROWS;
  int nb_node  = (n + 7) / 8;
  int nbhx = ((etot + FCE - 1) / FCE) * 8;      // XCD-partitioned hist blocks
  int nbx = (n * 32 + NT - 1) / NT;             // convx section blocks
  int nbw = (8 * DFEAT * DFEAT) / NT;           // convw section blocks
  int nb_fillx = ((etot + FCE - 1) / FCE) * 8;

  // ---- build merged CSR + dinv + packed edge weights ----
  (void)hipMemsetAsync(cnt_c, 0, (size_t)2 * n * 4, stream);
  megapre_k<<<nbhx + nbx + nbw, NT, 0, stream>>>(e_dst, E, c_dst, EC, cnt_c, cnt_t,
                                                 x0, xh, n * 32, Wc, Wt, wT,
                                                 nbhx, nbx, n);
  scan_partial_md<<<nb_scan, NT, 0, stream>>>(cnt_c, cnt_t, n, bsum, dall);
  scan_offsets_m<<<1, NT, 0, stream>>>(bsum, nb_scan, rp, n);
  scan_final_m<<<nb_scan, NT, 0, stream>>>(cnt_c, cnt_t, n, bsum, rp);
  fillx_k<<<nb_fillx, NT, 0, stream>>>(e_src, e_dst, E, c_src, c_dst, EC,
                                       dall, cnt_c, ecw, n);

  // ---- layers: merged-CSR aggregate (chunk-8, packed edges) + fused K=256 GEMM ----
  for (int i = 0; i < 4; i++) {
    aggregate9_k<<<nb_node, NT, 0, stream>>>(xh, rp, ecw, dall, agg_c, agg_t, n);
    gemmf_k<<<nb_gemm, NT, 0, stream>>>(agg_c, agg_t,
                                        wT + (size_t)i * DFEAT * DFEAT,
                                        wT + (size_t)(4 + i) * DFEAT * DFEAT,
                                        bc + i * DFEAT, bt + i * DFEAT,
                                        out, xh, n, (i == 3) ? 1 : 0);
  }
}